// Round 4
// baseline (2462.722 us; speedup 1.0000x reference)
//
#include <hip/hip_runtime.h>
#include <hip/hip_bf16.h>

namespace {

// ---- per-batch workspace layout (floats). H=16, N=4096, D=64, r=256 ----
constexpr size_t QKV1   = 4194304;                 // 16*4096*64 (one of q/k/v)
constexpr size_t Q_OFF  = 0;
constexpr size_t K_OFF  = QKV1;                    // also attn overlay (4096*1024)
constexpr size_t V_OFF  = 2 * QKV1;
constexpr size_t ATTN_OFF = K_OFF;                 // K dead after reduce
constexpr size_t KVP_OFF  = 3 * QKV1;              // [4 chunk][16 h][256 r][64 d]
constexpr size_t KVP_CH   = 262144;                // 16*256*64
constexpr size_t DPART_OFF = KVP_OFF + 4 * KVP_CH; // [4 chunk][16 h][256 r]
constexpr size_t DPART_CH = 4096;
constexpr size_t KV_OFF   = DPART_OFF + 4 * DPART_CH;
constexpr size_t DEN_OFF  = KV_OFF + KVP_CH;
constexpr size_t WS_ELEMS = DEN_OFF + DPART_CH;    // 13,914,112 floats (~55.7 MB)

// diagnostic sentinel: writes a recognizable fp32 value into out[0]
__global__ void k_sent(float* out, float v) { out[0] = v; }

// ---------------- Kernel 1: qkv(b) = x_b @ Wqkv^T + bqkv, scatter [t][h][n][d]
__global__ __launch_bounds__(256) void k_gemm_qkv(
    const float* __restrict__ x, const float* __restrict__ Wq,
    const float* __restrict__ bq, float* __restrict__ ws) {
  __shared__ float As[16][132];   // [k][m] transposed; 132*4B keeps f4 align
  __shared__ float Bs[16][132];
  const int t = threadIdx.x;
  const int tx = t & 15, ty = t >> 4;
  const int mBase = blockIdx.y * 128;              // n within batch
  const int jBase = blockIdx.x * 128;              // 3C col
  float acc[8][8] = {};
  for (int kt = 0; kt < 1024; kt += 16) {
    __syncthreads();
#pragma unroll
    for (int i = 0; i < 2; ++i) {
      int flat = t + i * 256;
      int row = flat >> 2, c4 = (flat & 3) * 4;
      float4 a = *(const float4*)&x[(size_t)(mBase + row) * 1024 + kt + c4];
      As[c4 + 0][row] = a.x; As[c4 + 1][row] = a.y;
      As[c4 + 2][row] = a.z; As[c4 + 3][row] = a.w;
      float4 b = *(const float4*)&Wq[(size_t)(jBase + row) * 1024 + kt + c4];
      Bs[c4 + 0][row] = b.x; Bs[c4 + 1][row] = b.y;
      Bs[c4 + 2][row] = b.z; Bs[c4 + 3][row] = b.w;
    }
    __syncthreads();
#pragma unroll
    for (int kk = 0; kk < 16; ++kk) {
      float4 a0 = *(const float4*)&As[kk][ty * 4];
      float4 a1 = *(const float4*)&As[kk][64 + ty * 4];
      float4 b0 = *(const float4*)&Bs[kk][tx * 4];
      float4 b1 = *(const float4*)&Bs[kk][64 + tx * 4];
      float av[8] = {a0.x, a0.y, a0.z, a0.w, a1.x, a1.y, a1.z, a1.w};
      float bv[8] = {b0.x, b0.y, b0.z, b0.w, b1.x, b1.y, b1.z, b1.w};
#pragma unroll
      for (int ii = 0; ii < 8; ++ii)
#pragma unroll
        for (int jj = 0; jj < 8; ++jj)
          acc[ii][jj] = fmaf(av[ii], bv[jj], acc[ii][jj]);
    }
  }
#pragma unroll
  for (int ih = 0; ih < 2; ++ih)
#pragma unroll
    for (int ii = 0; ii < 4; ++ii) {
      int n = mBase + ih * 64 + ty * 4 + ii;
#pragma unroll
      for (int jh = 0; jh < 2; ++jh) {
        int j = jBase + jh * 64 + tx * 4;
        int t3 = j >> 10, h = (j >> 6) & 15, dd = j & 63;
        float4 bias = *(const float4*)&bq[j];
        float4 o;
        o.x = acc[ih * 4 + ii][jh * 4 + 0] + bias.x;
        o.y = acc[ih * 4 + ii][jh * 4 + 1] + bias.y;
        o.z = acc[ih * 4 + ii][jh * 4 + 2] + bias.z;
        o.w = acc[ih * 4 + ii][jh * 4 + 3] + bias.w;
        size_t off = (size_t)t3 * QKV1 + (((size_t)h * 4096 + n) * 64 + dd);
        *(float4*)&ws[off] = o;
      }
    }
}

// ---------------- Kernel 2 (pass A): per (rc, nchunk, h): partial KV + denom
__global__ __launch_bounds__(256) void k_pass_a(
    const float* __restrict__ ws, const float* __restrict__ Wrm,
    float* __restrict__ kvp, float* __restrict__ dpart) {
  __shared__ float kT[64][33];    // [d][n] transposed (conflict-free proj reads)
  __shared__ float vL[32][68];
  __shared__ float wT[64][68];    // [d][r_local] transposed (f4 proj reads)
  __shared__ float phi[32][68];
  __shared__ float nsq[32];
  const int t = threadIdx.x;
  const int rc = blockIdx.x, ncu = blockIdx.y, h = blockIdx.z;
  const float* kb = ws + K_OFF + (size_t)h * (4096 * 64);
  const float* vb = ws + V_OFF + (size_t)h * (4096 * 64);
#pragma unroll
  for (int i = 0; i < 4; ++i) {   // stage W (once per block), transposed
    int flat = t + i * 256;
    int row = flat >> 4, c4 = (flat & 15) * 4;
    float4 w = *(const float4*)&Wrm[(rc * 64 + row) * 64 + c4];
    wT[c4 + 0][row] = w.x; wT[c4 + 1][row] = w.y;
    wT[c4 + 2][row] = w.z; wT[c4 + 3][row] = w.w;
  }
  const int ng = t & 15, rg = t >> 4;
  float acc[4][4] = {};
  float dacc[4] = {};
  for (int nb = 0; nb < 32; ++nb) {
    const int n0 = ncu * 1024 + nb * 32;
    __syncthreads();
    float sq0, sq1;
    {
      int row0 = t >> 4, c4 = (t & 15) * 4;
      float4 k0 = *(const float4*)&kb[(size_t)(n0 + row0) * 64 + c4];
      kT[c4 + 0][row0] = k0.x; kT[c4 + 1][row0] = k0.y;
      kT[c4 + 2][row0] = k0.z; kT[c4 + 3][row0] = k0.w;
      sq0 = k0.x * k0.x + k0.y * k0.y + k0.z * k0.z + k0.w * k0.w;
      *(float4*)&vL[row0][c4] = *(const float4*)&vb[(size_t)(n0 + row0) * 64 + c4];
      int row1 = 16 + row0;
      float4 k1 = *(const float4*)&kb[(size_t)(n0 + row1) * 64 + c4];
      kT[c4 + 0][row1] = k1.x; kT[c4 + 1][row1] = k1.y;
      kT[c4 + 2][row1] = k1.z; kT[c4 + 3][row1] = k1.w;
      sq1 = k1.x * k1.x + k1.y * k1.y + k1.z * k1.z + k1.w * k1.w;
      *(float4*)&vL[row1][c4] = *(const float4*)&vb[(size_t)(n0 + row1) * 64 + c4];
    }
#pragma unroll
    for (int s = 1; s < 16; s <<= 1) {   // reduce ||row||^2 over 16-lane groups
      sq0 += __shfl_xor(sq0, s);
      sq1 += __shfl_xor(sq1, s);
    }
    if ((t & 15) == 0) { nsq[t >> 4] = 0.5f * sq0; nsq[16 + (t >> 4)] = 0.5f * sq1; }
    __syncthreads();
    {   // proj (2 rows x 4 feats per thread) -> phi
      float p0[4] = {}, p1[4] = {};
#pragma unroll 8
      for (int kk = 0; kk < 64; ++kk) {
        float k0 = kT[kk][2 * ng], k1 = kT[kk][2 * ng + 1];
        float4 w4 = *(const float4*)&wT[kk][4 * rg];
        p0[0] = fmaf(k0, w4.x, p0[0]); p0[1] = fmaf(k0, w4.y, p0[1]);
        p0[2] = fmaf(k0, w4.z, p0[2]); p0[3] = fmaf(k0, w4.w, p0[3]);
        p1[0] = fmaf(k1, w4.x, p1[0]); p1[1] = fmaf(k1, w4.y, p1[1]);
        p1[2] = fmaf(k1, w4.z, p1[2]); p1[3] = fmaf(k1, w4.w, p1[3]);
      }
      float ns0 = nsq[2 * ng], ns1 = nsq[2 * ng + 1];
      float4 f0, f1;
      f0.x = __expf(p0[0] - ns0) * 0.0625f;
      f0.y = __expf(p0[1] - ns0) * 0.0625f;
      f0.z = __expf(p0[2] - ns0) * 0.0625f;
      f0.w = __expf(p0[3] - ns0) * 0.0625f;
      f1.x = __expf(p1[0] - ns1) * 0.0625f;
      f1.y = __expf(p1[1] - ns1) * 0.0625f;
      f1.z = __expf(p1[2] - ns1) * 0.0625f;
      f1.w = __expf(p1[3] - ns1) * 0.0625f;
      *(float4*)&phi[2 * ng][4 * rg] = f0;
      *(float4*)&phi[2 * ng + 1][4 * rg] = f1;
    }
    __syncthreads();
#pragma unroll 8
    for (int n = 0; n < 32; ++n) {   // rank-1 accumulate kv += phi (x) v
      float4 p4 = *(const float4*)&phi[n][4 * rg];
      float4 v4 = *(const float4*)&vL[n][4 * ng];
      float pv[4] = {p4.x, p4.y, p4.z, p4.w};
      float vv[4] = {v4.x, v4.y, v4.z, v4.w};
#pragma unroll
      for (int i = 0; i < 4; ++i) {
        dacc[i] += pv[i];
#pragma unroll
        for (int j = 0; j < 4; ++j) acc[i][j] = fmaf(pv[i], vv[j], acc[i][j]);
      }
    }
  }
  // kvp: [ncu][h][r][d]; chunk stride = 16*256*64 = KVP_CH
  size_t base = (((size_t)ncu * 16 + h) * 256 + rc * 64 + 4 * rg) * 64 + 4 * ng;
#pragma unroll
  for (int i = 0; i < 4; ++i) {
    float4 o = {acc[i][0], acc[i][1], acc[i][2], acc[i][3]};
    *(float4*)&kvp[base + (size_t)i * 64] = o;
  }
  if (ng == 0) {
    size_t db = ((size_t)ncu * 16 + h) * 256 + rc * 64 + 4 * rg;
#pragma unroll
    for (int i = 0; i < 4; ++i) dpart[db + i] = dacc[i];
  }
}

// ---------------- Kernel 3: deterministic partial reduction (kv + denom)
__global__ __launch_bounds__(256) void k_reduce(float* __restrict__ ws) {
  size_t i = (size_t)blockIdx.x * 256 + threadIdx.x;
  if (i < KVP_CH) {
    float s = 0.f;
#pragma unroll
    for (int c = 0; c < 4; ++c) s += ws[KVP_OFF + c * KVP_CH + i];
    ws[KV_OFF + i] = s;
  } else {
    size_t j = i - KVP_CH;
    float s = 0.f;
#pragma unroll
    for (int c = 0; c < 4; ++c) s += ws[DPART_OFF + c * DPART_CH + j];
    ws[DEN_OFF + j] = s;
  }
}

// ---------------- Kernel 4 (pass B): phi_q on the fly, num/den, normalize
__global__ __launch_bounds__(256) void k_pass_b(
    const float* __restrict__ ws, const float* __restrict__ Wrm,
    float* __restrict__ attn) {
  __shared__ float qT[64][33];
  __shared__ float wT[64][68];
  __shared__ float kvL[64][68];
  __shared__ float phi[32][68];
  __shared__ float denL[64];
  __shared__ float nsq[32];
  const int t = threadIdx.x;
  const int nb = blockIdx.x, h = blockIdx.y;
  const int n0 = nb * 32;
  const float* qb = ws + Q_OFF + (size_t)h * (4096 * 64);
  const float* kv = ws + KV_OFF + (size_t)h * 16384;
  const float* dv = ws + DEN_OFF + (size_t)h * 256;
  float sq0, sq1;
  {
    int row0 = t >> 4, c4 = (t & 15) * 4;
    float4 q0 = *(const float4*)&qb[(size_t)(n0 + row0) * 64 + c4];
    qT[c4 + 0][row0] = q0.x; qT[c4 + 1][row0] = q0.y;
    qT[c4 + 2][row0] = q0.z; qT[c4 + 3][row0] = q0.w;
    sq0 = q0.x * q0.x + q0.y * q0.y + q0.z * q0.z + q0.w * q0.w;
    int row1 = 16 + row0;
    float4 q1 = *(const float4*)&qb[(size_t)(n0 + row1) * 64 + c4];
    qT[c4 + 0][row1] = q1.x; qT[c4 + 1][row1] = q1.y;
    qT[c4 + 2][row1] = q1.z; qT[c4 + 3][row1] = q1.w;
    sq1 = q1.x * q1.x + q1.y * q1.y + q1.z * q1.z + q1.w * q1.w;
  }
#pragma unroll
  for (int s = 1; s < 16; s <<= 1) {
    sq0 += __shfl_xor(sq0, s);
    sq1 += __shfl_xor(sq1, s);
  }
  if ((t & 15) == 0) { nsq[t >> 4] = 0.5f * sq0; nsq[16 + (t >> 4)] = 0.5f * sq1; }
  const int ng = t & 15, rg = t >> 4;
  float acc[2][4] = {};
  float dacc[2] = {};
  for (int rc = 0; rc < 4; ++rc) {
    __syncthreads();
#pragma unroll
    for (int i = 0; i < 4; ++i) {
      int flat = t + i * 256;
      int row = flat >> 4, c4 = (flat & 15) * 4;
      float4 w = *(const float4*)&Wrm[(rc * 64 + row) * 64 + c4];
      wT[c4 + 0][row] = w.x; wT[c4 + 1][row] = w.y;
      wT[c4 + 2][row] = w.z; wT[c4 + 3][row] = w.w;
      *(float4*)&kvL[row][c4] =
          *(const float4*)&kv[(size_t)(rc * 64 + row) * 64 + c4];
    }
    if (t < 64) denL[t] = dv[rc * 64 + t];
    __syncthreads();
    float p0[4] = {}, p1[4] = {};
#pragma unroll 8
    for (int kk = 0; kk < 64; ++kk) {
      float q0 = qT[kk][2 * ng], q1 = qT[kk][2 * ng + 1];
      float4 w4 = *(const float4*)&wT[kk][4 * rg];
      p0[0] = fmaf(q0, w4.x, p0[0]); p0[1] = fmaf(q0, w4.y, p0[1]);
      p0[2] = fmaf(q0, w4.z, p0[2]); p0[3] = fmaf(q0, w4.w, p0[3]);
      p1[0] = fmaf(q1, w4.x, p1[0]); p1[1] = fmaf(q1, w4.y, p1[1]);
      p1[2] = fmaf(q1, w4.z, p1[2]); p1[3] = fmaf(q1, w4.w, p1[3]);
    }
    {
      float ns0 = nsq[2 * ng], ns1 = nsq[2 * ng + 1];
      float4 f0, f1;
      f0.x = __expf(p0[0] - ns0) * 0.0625f;
      f0.y = __expf(p0[1] - ns0) * 0.0625f;
      f0.z = __expf(p0[2] - ns0) * 0.0625f;
      f0.w = __expf(p0[3] - ns0) * 0.0625f;
      f1.x = __expf(p1[0] - ns1) * 0.0625f;
      f1.y = __expf(p1[1] - ns1) * 0.0625f;
      f1.z = __expf(p1[2] - ns1) * 0.0625f;
      f1.w = __expf(p1[3] - ns1) * 0.0625f;
      *(float4*)&phi[2 * ng][4 * rg] = f0;
      *(float4*)&phi[2 * ng + 1][4 * rg] = f1;
    }
    __syncthreads();
#pragma unroll 4
    for (int rl = 0; rl < 64; ++rl) {
      float pa = phi[2 * rg][rl], pb = phi[2 * rg + 1][rl];
      float4 k4 = *(const float4*)&kvL[rl][4 * ng];
      float dn = denL[rl];
      acc[0][0] = fmaf(pa, k4.x, acc[0][0]);
      acc[0][1] = fmaf(pa, k4.y, acc[0][1]);
      acc[0][2] = fmaf(pa, k4.z, acc[0][2]);
      acc[0][3] = fmaf(pa, k4.w, acc[0][3]);
      acc[1][0] = fmaf(pb, k4.x, acc[1][0]);
      acc[1][1] = fmaf(pb, k4.y, acc[1][1]);
      acc[1][2] = fmaf(pb, k4.z, acc[1][2]);
      acc[1][3] = fmaf(pb, k4.w, acc[1][3]);
      dacc[0] = fmaf(pa, dn, dacc[0]);
      dacc[1] = fmaf(pb, dn, dacc[1]);
    }
  }
#pragma unroll
  for (int i = 0; i < 2; ++i) {
    int n = n0 + 2 * rg + i;
    float inv = 1.0f / (dacc[i] + 1e-6f);
    float4 o = {acc[i][0] * inv, acc[i][1] * inv, acc[i][2] * inv,
                acc[i][3] * inv};
    *(float4*)&attn[((size_t)n) * 1024 + h * 64 + 4 * ng] = o;
  }
}

// ---------------- Kernel 5: out_b = attn @ Wproj^T + bproj -> FP32
__global__ __launch_bounds__(256) void k_gemm_out(
    const float* __restrict__ attn, const float* __restrict__ Wp,
    const float* __restrict__ bp, float* __restrict__ out) {
  __shared__ float As[16][132];
  __shared__ float Bs[16][132];
  const int t = threadIdx.x;
  const int tx = t & 15, ty = t >> 4;
  const int mBase = blockIdx.y * 128;
  const int jBase = blockIdx.x * 128;
  float acc[8][8] = {};
  for (int kt = 0; kt < 1024; kt += 16) {
    __syncthreads();
#pragma unroll
    for (int i = 0; i < 2; ++i) {
      int flat = t + i * 256;
      int row = flat >> 2, c4 = (flat & 3) * 4;
      float4 a = *(const float4*)&attn[(size_t)(mBase + row) * 1024 + kt + c4];
      As[c4 + 0][row] = a.x; As[c4 + 1][row] = a.y;
      As[c4 + 2][row] = a.z; As[c4 + 3][row] = a.w;
      float4 b = *(const float4*)&Wp[(size_t)(jBase + row) * 1024 + kt + c4];
      Bs[c4 + 0][row] = b.x; Bs[c4 + 1][row] = b.y;
      Bs[c4 + 2][row] = b.z; Bs[c4 + 3][row] = b.w;
    }
    __syncthreads();
#pragma unroll
    for (int kk = 0; kk < 16; ++kk) {
      float4 a0 = *(const float4*)&As[kk][ty * 4];
      float4 a1 = *(const float4*)&As[kk][64 + ty * 4];
      float4 b0 = *(const float4*)&Bs[kk][tx * 4];
      float4 b1 = *(const float4*)&Bs[kk][64 + tx * 4];
      float av[8] = {a0.x, a0.y, a0.z, a0.w, a1.x, a1.y, a1.z, a1.w};
      float bv[8] = {b0.x, b0.y, b0.z, b0.w, b1.x, b1.y, b1.z, b1.w};
#pragma unroll
      for (int ii = 0; ii < 8; ++ii)
#pragma unroll
        for (int jj = 0; jj < 8; ++jj)
          acc[ii][jj] = fmaf(av[ii], bv[jj], acc[ii][jj]);
    }
  }
#pragma unroll
  for (int ih = 0; ih < 2; ++ih)
#pragma unroll
    for (int ii = 0; ii < 4; ++ii) {
      int m = mBase + ih * 64 + ty * 4 + ii;
#pragma unroll
      for (int jh = 0; jh < 2; ++jh) {
        int j = jBase + jh * 64 + tx * 4;
        float4 bias = *(const float4*)&bp[j];
        float4 o;
        o.x = acc[ih * 4 + ii][jh * 4 + 0] + bias.x;
        o.y = acc[ih * 4 + ii][jh * 4 + 1] + bias.y;
        o.z = acc[ih * 4 + ii][jh * 4 + 2] + bias.z;
        o.w = acc[ih * 4 + ii][jh * 4 + 3] + bias.w;
        *(float4*)&out[(size_t)m * 1024 + j] = o;
      }
    }
}

}  // namespace

extern "C" void kernel_launch(void* const* d_in, const int* in_sizes, int n_in,
                              void* d_out, int out_size, void* d_ws,
                              size_t ws_size, hipStream_t stream) {
  // Identify inputs by element count (robust to ordering assumptions).
  const float *x = nullptr, *Wqkv = nullptr, *bqkv = nullptr;
  const float *Wproj = nullptr, *bproj = nullptr, *Wrm = nullptr;
  for (int i = 0; i < n_in; ++i) {
    switch (in_sizes[i]) {
      case 16777216: x     = (const float*)d_in[i]; break;  // [4,4096,1024]
      case 3145728:  Wqkv  = (const float*)d_in[i]; break;  // [3072,1024]
      case 3072:     bqkv  = (const float*)d_in[i]; break;
      case 1048576:  Wproj = (const float*)d_in[i]; break;  // [1024,1024]
      case 1024:     bproj = (const float*)d_in[i]; break;
      case 16384:    Wrm   = (const float*)d_in[i]; break;  // [256,64]
      default: break;
    }
  }
  float* out = (float*)d_out;   // reference output dtype is float32
  float* ws = (float*)d_ws;

  if (!x || !Wqkv || !bqkv || !Wproj || !bproj || !Wrm) {
    k_sent<<<1, 1, 0, stream>>>(out, 2000.0f);  // "inputs unexpected"
    return;
  }
  if (ws_size < WS_ELEMS * sizeof(float)) {
    k_sent<<<1, 1, 0, stream>>>(out, 1000.0f);  // "ws too small"
    return;
  }

  for (int b = 0; b < 4; ++b) {
    const float* x_b = x + (size_t)b * 4096 * 1024;
    float* out_b = out + (size_t)b * 4096 * 1024;
    // 1) qkv projection GEMM (25.8 GF/batch) -> q/k/v in [h][n][d]
    k_gemm_qkv<<<dim3(24, 32), 256, 0, stream>>>(x_b, Wqkv, bqkv, ws);
    // 2) pass A: phi_k on the fly, partial KV[256x64] + denom per (rc,ncu,h)
    k_pass_a<<<dim3(4, 4, 16), 256, 0, stream>>>(ws, Wrm, ws + KVP_OFF,
                                                 ws + DPART_OFF);
    // 3) deterministic reduction of the 4 N-chunks (262144+4096 -> 1040 blocks)
    k_reduce<<<1040, 256, 0, stream>>>(ws);
    // 4) pass B: phi_q on the fly, num/den, normalize -> attn [N][C] overlay K
    k_pass_b<<<dim3(128, 16), 256, 0, stream>>>(ws, Wrm, ws + ATTN_OFF);
    // 5) output projection GEMM (8.6 GF/batch) -> fp32
    k_gemm_out<<<dim3(8, 32), 256, 0, stream>>>(ws + ATTN_OFF, Wproj, bproj,
                                                out_b);
  }
}

// Round 5
// 1040.955 us; speedup vs baseline: 2.3658x; 2.3658x over previous
//
#include <hip/hip_runtime.h>
#include <hip/hip_bf16.h>

namespace {

typedef __attribute__((ext_vector_type(8))) short short8v;   // 8 bf16
typedef __attribute__((ext_vector_type(4))) float float4v;   // 4 f32

// ---- per-batch fp32 workspace layout (floats). H=16, N=4096, D=64, r=256 ----
constexpr size_t QKV1     = 4194304;                    // 16*4096*64
constexpr size_t Q_OFF    = 0;
constexpr size_t K_OFF    = QKV1;
constexpr size_t V_OFF    = 2 * QKV1;
constexpr int    NCHUNK   = 16;
constexpr size_t KVP_OFF  = 3 * QKV1;                   // [16 chunk][16 h][256 r][64 d]
constexpr size_t KVP_CH   = 262144;                     // 16*256*64
constexpr size_t DPART_OFF = KVP_OFF + NCHUNK * KVP_CH; // [16 chunk][16 h][256 r]
constexpr size_t DPART_CH = 4096;
constexpr size_t KV_OFF   = DPART_OFF + NCHUNK * DPART_CH;
constexpr size_t DEN_OFF  = KV_OFF + KVP_CH;
// bf16 staging (float-offsets; each float slot = 2 ushorts)
constexpr size_t XH_OFF   = DEN_OFF + DPART_CH;         // x_hi  4096*1024 ushorts
constexpr size_t XL_OFF   = XH_OFF + 2097152;           // x_lo
constexpr size_t WH_OFF   = XL_OFF + 2097152;           // Wqkv_hi 3072*1024 ushorts
constexpr size_t WL_OFF   = WH_OFF + 1572864;           // Wqkv_lo
constexpr size_t ATTNB_OFF = WL_OFF + 1572864;          // attn bf16 all 4 batches
constexpr size_t WPH_OFF  = ATTNB_OFF + 8388608;        // Wproj_hi 1024*1024 ushorts
constexpr size_t WS_ELEMS = WPH_OFF + 524288;           // 33,361,920 floats (~133 MB)

__device__ __forceinline__ unsigned short f2bf(float f) {
  unsigned int u = __float_as_uint(f);
  u += 0x7FFFu + ((u >> 16) & 1u);                      // round-to-nearest-even
  return (unsigned short)(u >> 16);
}

__global__ void k_sent(float* out, float v) { out[0] = v; }

// ---------------- fp32 -> bf16 hi+lo split (3-MFMA precision recovery)
__global__ __launch_bounds__(256) void k_conv_split(
    const float* __restrict__ src, unsigned short* __restrict__ hi,
    unsigned short* __restrict__ lo, int n4) {
  int i = blockIdx.x * 256 + threadIdx.x;
  if (i >= n4) return;
  float4 v = *(const float4*)&src[(size_t)i * 4];
  ushort4 h, l;
  h.x = f2bf(v.x); l.x = f2bf(v.x - __uint_as_float((unsigned)h.x << 16));
  h.y = f2bf(v.y); l.y = f2bf(v.y - __uint_as_float((unsigned)h.y << 16));
  h.z = f2bf(v.z); l.z = f2bf(v.z - __uint_as_float((unsigned)h.z << 16));
  h.w = f2bf(v.w); l.w = f2bf(v.w - __uint_as_float((unsigned)h.w << 16));
  *(ushort4*)&hi[(size_t)i * 4] = h;
  *(ushort4*)&lo[(size_t)i * 4] = l;
}

__global__ __launch_bounds__(256) void k_conv_hi(
    const float* __restrict__ src, unsigned short* __restrict__ hi, int n4) {
  int i = blockIdx.x * 256 + threadIdx.x;
  if (i >= n4) return;
  float4 v = *(const float4*)&src[(size_t)i * 4];
  ushort4 h = {f2bf(v.x), f2bf(v.y), f2bf(v.z), f2bf(v.w)};
  *(ushort4*)&hi[(size_t)i * 4] = h;
}

// ---- stage a [128 rows][64 k] bf16 tile to LDS via global_load_lds.
// LDS dest linear in 16B chunks; global source pre-swizzled so that a
// swizzled read (seg ^ (row&7)) round-trips (rule: both-sides-or-neither).
__device__ __forceinline__ void stage_tile(const unsigned short* __restrict__ src,
                                           unsigned short* __restrict__ dst,
                                           int t) {
#pragma unroll
  for (int i = 0; i < 4; ++i) {
    int c = i * 256 + t;                 // 16B chunk id, 0..1023
    int row = c >> 3;
    int seg = (c & 7) ^ (row & 7);       // inverse-swizzled global segment
    __builtin_amdgcn_global_load_lds(
        (const __attribute__((address_space(1))) void*)(src + (size_t)row * 1024 + seg * 8),
        (__attribute__((address_space(3))) void*)(dst + (size_t)c * 8),
        16, 0, 0);
  }
}

__device__ __forceinline__ short8v read_frag(const unsigned short* lds, int row,
                                             int seg) {
  return *(const short8v*)&lds[(size_t)row * 64 + ((seg ^ (row & 7)) * 8)];
}

// ---------------- qkv GEMM, split-bf16 (acc = xh@wh + xh@wl + xl@wh)
// M=4096(n) N=3072(j) K=1024; scatter fp32 to q/k/v [t3][h][n][d] + bias
__global__ __launch_bounds__(256, 2) void k_qkv_mfma(
    const unsigned short* __restrict__ xh, const unsigned short* __restrict__ xl,
    const unsigned short* __restrict__ wh, const unsigned short* __restrict__ wl,
    const float* __restrict__ bq, float* __restrict__ ws) {
  __shared__ unsigned short ldsA[2][8192];   // hi, lo : 128x64 bf16 each
  __shared__ unsigned short ldsB[2][8192];
  const int t = threadIdx.x;
  const int lane = t & 63, wv = t >> 6;
  const int wm = wv >> 1, wn = wv & 1;       // 2x2 wave grid, 64x64 per wave
  const int lr = lane & 15, lg = lane >> 4;
  const int mBase = blockIdx.y * 128;
  const int jBase = blockIdx.x * 128;
  float4v acc[4][4];
#pragma unroll
  for (int a = 0; a < 4; ++a)
#pragma unroll
    for (int b = 0; b < 4; ++b) acc[a][b] = (float4v){0.f, 0.f, 0.f, 0.f};

  for (int kt = 0; kt < 1024; kt += 64) {
    __syncthreads();
    stage_tile(xh + (size_t)mBase * 1024 + kt, ldsA[0], t);
    stage_tile(xl + (size_t)mBase * 1024 + kt, ldsA[1], t);
    stage_tile(wh + (size_t)jBase * 1024 + kt, ldsB[0], t);
    stage_tile(wl + (size_t)jBase * 1024 + kt, ldsB[1], t);
    asm volatile("s_waitcnt vmcnt(0)");
    __syncthreads();
#pragma unroll
    for (int ks = 0; ks < 2; ++ks) {
      const int seg = ks * 4 + lg;
      short8v ah[4], al[4], bh[4], bl[4];
#pragma unroll
      for (int f = 0; f < 4; ++f) {
        int ra = wm * 64 + f * 16 + lr;
        ah[f] = read_frag(ldsA[0], ra, seg);
        al[f] = read_frag(ldsA[1], ra, seg);
        int rb = wn * 64 + f * 16 + lr;
        bh[f] = read_frag(ldsB[0], rb, seg);
        bl[f] = read_frag(ldsB[1], rb, seg);
      }
#pragma unroll
      for (int fm = 0; fm < 4; ++fm)
#pragma unroll
        for (int fn = 0; fn < 4; ++fn) {
          acc[fm][fn] = __builtin_amdgcn_mfma_f32_16x16x32_bf16(
              ah[fm], bh[fn], acc[fm][fn], 0, 0, 0);
          acc[fm][fn] = __builtin_amdgcn_mfma_f32_16x16x32_bf16(
              ah[fm], bl[fn], acc[fm][fn], 0, 0, 0);
          acc[fm][fn] = __builtin_amdgcn_mfma_f32_16x16x32_bf16(
              al[fm], bh[fn], acc[fm][fn], 0, 0, 0);
        }
    }
  }
  // epilogue: D frag layout col=lane&15, row=(lane>>4)*4+reg (m89-verified)
#pragma unroll
  for (int fn = 0; fn < 4; ++fn) {
    int j = jBase + wn * 64 + fn * 16 + lr;
    int t3 = j >> 10, h = (j >> 6) & 15, dd = j & 63;
    float bias = bq[j];
    float* op = ws + (size_t)t3 * QKV1 + (size_t)h * 262144 + dd;
#pragma unroll
    for (int fm = 0; fm < 4; ++fm) {
      int n0 = mBase + wm * 64 + fm * 16 + lg * 4;
#pragma unroll
      for (int r = 0; r < 4; ++r)
        op[(size_t)(n0 + r) * 64] = acc[fm][fn][r] + bias;
    }
  }
}

// ---------------- out GEMM, plain bf16: out = attnb @ wproj^T + bproj (fp32)
// M=16384 (all batches) N=1024 K=1024
__global__ __launch_bounds__(256, 2) void k_out_mfma(
    const unsigned short* __restrict__ ab, const unsigned short* __restrict__ wp,
    const float* __restrict__ bp, float* __restrict__ out) {
  __shared__ unsigned short ldsA[8192];
  __shared__ unsigned short ldsB[8192];
  const int t = threadIdx.x;
  const int lane = t & 63, wv = t >> 6;
  const int wm = wv >> 1, wn = wv & 1;
  const int lr = lane & 15, lg = lane >> 4;
  const int mBase = blockIdx.y * 128;
  const int jBase = blockIdx.x * 128;
  float4v acc[4][4];
#pragma unroll
  for (int a = 0; a < 4; ++a)
#pragma unroll
    for (int b = 0; b < 4; ++b) acc[a][b] = (float4v){0.f, 0.f, 0.f, 0.f};

  for (int kt = 0; kt < 1024; kt += 64) {
    __syncthreads();
    stage_tile(ab + (size_t)mBase * 1024 + kt, ldsA, t);
    stage_tile(wp + (size_t)jBase * 1024 + kt, ldsB, t);
    asm volatile("s_waitcnt vmcnt(0)");
    __syncthreads();
#pragma unroll
    for (int ks = 0; ks < 2; ++ks) {
      const int seg = ks * 4 + lg;
      short8v a[4], b[4];
#pragma unroll
      for (int f = 0; f < 4; ++f) {
        a[f] = read_frag(ldsA, wm * 64 + f * 16 + lr, seg);
        b[f] = read_frag(ldsB, wn * 64 + f * 16 + lr, seg);
      }
#pragma unroll
      for (int fm = 0; fm < 4; ++fm)
#pragma unroll
        for (int fn = 0; fn < 4; ++fn)
          acc[fm][fn] = __builtin_amdgcn_mfma_f32_16x16x32_bf16(
              a[fm], b[fn], acc[fm][fn], 0, 0, 0);
    }
  }
#pragma unroll
  for (int fn = 0; fn < 4; ++fn) {
    int j = jBase + wn * 64 + fn * 16 + lr;
    float bias = bp[j];
#pragma unroll
    for (int fm = 0; fm < 4; ++fm) {
      int m0 = mBase + wm * 64 + fm * 16 + lg * 4;
#pragma unroll
      for (int r = 0; r < 4; ++r)
        out[(size_t)(m0 + r) * 1024 + j] = acc[fm][fn][r] + bias;
    }
  }
}

// ---------------- pass A: per (rc, nchunk, h): partial KV + denom (fp32)
__global__ __launch_bounds__(256) void k_pass_a(
    const float* __restrict__ ws, const float* __restrict__ Wrm,
    float* __restrict__ kvp, float* __restrict__ dpart) {
  __shared__ float kT[64][33];
  __shared__ float vL[32][68];
  __shared__ float wT[64][68];
  __shared__ float phi[32][68];
  __shared__ float nsq[32];
  const int t = threadIdx.x;
  const int rc = blockIdx.x, ncu = blockIdx.y, h = blockIdx.z;
  const float* kb = ws + K_OFF + (size_t)h * (4096 * 64);
  const float* vb = ws + V_OFF + (size_t)h * (4096 * 64);
#pragma unroll
  for (int i = 0; i < 4; ++i) {
    int flat = t + i * 256;
    int row = flat >> 4, c4 = (flat & 15) * 4;
    float4 w = *(const float4*)&Wrm[(rc * 64 + row) * 64 + c4];
    wT[c4 + 0][row] = w.x; wT[c4 + 1][row] = w.y;
    wT[c4 + 2][row] = w.z; wT[c4 + 3][row] = w.w;
  }
  const int ng = t & 15, rg = t >> 4;
  float acc[4][4] = {};
  float dacc[4] = {};
  for (int nb = 0; nb < 8; ++nb) {              // 256 rows per chunk
    const int n0 = ncu * 256 + nb * 32;
    __syncthreads();
    float sq0, sq1;
    {
      int row0 = t >> 4, c4 = (t & 15) * 4;
      float4 k0 = *(const float4*)&kb[(size_t)(n0 + row0) * 64 + c4];
      kT[c4 + 0][row0] = k0.x; kT[c4 + 1][row0] = k0.y;
      kT[c4 + 2][row0] = k0.z; kT[c4 + 3][row0] = k0.w;
      sq0 = k0.x * k0.x + k0.y * k0.y + k0.z * k0.z + k0.w * k0.w;
      *(float4*)&vL[row0][c4] = *(const float4*)&vb[(size_t)(n0 + row0) * 64 + c4];
      int row1 = 16 + row0;
      float4 k1 = *(const float4*)&kb[(size_t)(n0 + row1) * 64 + c4];
      kT[c4 + 0][row1] = k1.x; kT[c4 + 1][row1] = k1.y;
      kT[c4 + 2][row1] = k1.z; kT[c4 + 3][row1] = k1.w;
      sq1 = k1.x * k1.x + k1.y * k1.y + k1.z * k1.z + k1.w * k1.w;
      *(float4*)&vL[row1][c4] = *(const float4*)&vb[(size_t)(n0 + row1) * 64 + c4];
    }
#pragma unroll
    for (int s = 1; s < 16; s <<= 1) {
      sq0 += __shfl_xor(sq0, s);
      sq1 += __shfl_xor(sq1, s);
    }
    if ((t & 15) == 0) { nsq[t >> 4] = 0.5f * sq0; nsq[16 + (t >> 4)] = 0.5f * sq1; }
    __syncthreads();
    {
      float p0[4] = {}, p1[4] = {};
#pragma unroll 8
      for (int kk = 0; kk < 64; ++kk) {
        float k0 = kT[kk][2 * ng], k1 = kT[kk][2 * ng + 1];
        float4 w4 = *(const float4*)&wT[kk][4 * rg];
        p0[0] = fmaf(k0, w4.x, p0[0]); p0[1] = fmaf(k0, w4.y, p0[1]);
        p0[2] = fmaf(k0, w4.z, p0[2]); p0[3] = fmaf(k0, w4.w, p0[3]);
        p1[0] = fmaf(k1, w4.x, p1[0]); p1[1] = fmaf(k1, w4.y, p1[1]);
        p1[2] = fmaf(k1, w4.z, p1[2]); p1[3] = fmaf(k1, w4.w, p1[3]);
      }
      float ns0 = nsq[2 * ng], ns1 = nsq[2 * ng + 1];
      float4 f0, f1;
      f0.x = __expf(p0[0] - ns0) * 0.0625f;
      f0.y = __expf(p0[1] - ns0) * 0.0625f;
      f0.z = __expf(p0[2] - ns0) * 0.0625f;
      f0.w = __expf(p0[3] - ns0) * 0.0625f;
      f1.x = __expf(p1[0] - ns1) * 0.0625f;
      f1.y = __expf(p1[1] - ns1) * 0.0625f;
      f1.z = __expf(p1[2] - ns1) * 0.0625f;
      f1.w = __expf(p1[3] - ns1) * 0.0625f;
      *(float4*)&phi[2 * ng][4 * rg] = f0;
      *(float4*)&phi[2 * ng + 1][4 * rg] = f1;
    }
    __syncthreads();
#pragma unroll 8
    for (int n = 0; n < 32; ++n) {
      float4 p4 = *(const float4*)&phi[n][4 * rg];
      float4 v4 = *(const float4*)&vL[n][4 * ng];
      float pv[4] = {p4.x, p4.y, p4.z, p4.w};
      float vv[4] = {v4.x, v4.y, v4.z, v4.w};
#pragma unroll
      for (int i = 0; i < 4; ++i) {
        dacc[i] += pv[i];
#pragma unroll
        for (int j = 0; j < 4; ++j) acc[i][j] = fmaf(pv[i], vv[j], acc[i][j]);
      }
    }
  }
  size_t base = (((size_t)ncu * 16 + h) * 256 + rc * 64 + 4 * rg) * 64 + 4 * ng;
#pragma unroll
  for (int i = 0; i < 4; ++i) {
    float4 o = {acc[i][0], acc[i][1], acc[i][2], acc[i][3]};
    *(float4*)&kvp[base + (size_t)i * 64] = o;
  }
  if (ng == 0) {
    size_t db = ((size_t)ncu * 16 + h) * 256 + rc * 64 + 4 * rg;
#pragma unroll
    for (int i = 0; i < 4; ++i) dpart[db + i] = dacc[i];
  }
}

// ---------------- deterministic partial reduction (kv + denom)
__global__ __launch_bounds__(256) void k_reduce(float* __restrict__ ws) {
  size_t i = (size_t)blockIdx.x * 256 + threadIdx.x;
  if (i < KVP_CH) {
    float s = 0.f;
#pragma unroll
    for (int c = 0; c < NCHUNK; ++c) s += ws[KVP_OFF + c * KVP_CH + i];
    ws[KV_OFF + i] = s;
  } else if (i < KVP_CH + DPART_CH) {
    size_t j = i - KVP_CH;
    float s = 0.f;
#pragma unroll
    for (int c = 0; c < NCHUNK; ++c) s += ws[DPART_OFF + c * DPART_CH + j];
    ws[DEN_OFF + j] = s;
  }
}

// ---------------- pass B: phi_q on the fly, num/den, normalize -> bf16 attn
__global__ __launch_bounds__(256) void k_pass_b(
    const float* __restrict__ ws, const float* __restrict__ Wrm,
    unsigned short* __restrict__ attnb) {
  __shared__ float qT[64][33];
  __shared__ float wT[64][68];
  __shared__ float kvL[64][68];
  __shared__ float phi[32][68];
  __shared__ float denL[64];
  __shared__ float nsq[32];
  const int t = threadIdx.x;
  const int nb = blockIdx.x, h = blockIdx.y;
  const int n0 = nb * 32;
  const float* qb = ws + Q_OFF + (size_t)h * (4096 * 64);
  const float* kv = ws + KV_OFF + (size_t)h * 16384;
  const float* dv = ws + DEN_OFF + (size_t)h * 256;
  float sq0, sq1;
  {
    int row0 = t >> 4, c4 = (t & 15) * 4;
    float4 q0 = *(const float4*)&qb[(size_t)(n0 + row0) * 64 + c4];
    qT[c4 + 0][row0] = q0.x; qT[c4 + 1][row0] = q0.y;
    qT[c4 + 2][row0] = q0.z; qT[c4 + 3][row0] = q0.w;
    sq0 = q0.x * q0.x + q0.y * q0.y + q0.z * q0.z + q0.w * q0.w;
    int row1 = 16 + row0;
    float4 q1 = *(const float4*)&qb[(size_t)(n0 + row1) * 64 + c4];
    qT[c4 + 0][row1] = q1.x; qT[c4 + 1][row1] = q1.y;
    qT[c4 + 2][row1] = q1.z; qT[c4 + 3][row1] = q1.w;
    sq1 = q1.x * q1.x + q1.y * q1.y + q1.z * q1.z + q1.w * q1.w;
  }
#pragma unroll
  for (int s = 1; s < 16; s <<= 1) {
    sq0 += __shfl_xor(sq0, s);
    sq1 += __shfl_xor(sq1, s);
  }
  if ((t & 15) == 0) { nsq[t >> 4] = 0.5f * sq0; nsq[16 + (t >> 4)] = 0.5f * sq1; }
  const int ng = t & 15, rg = t >> 4;
  float acc[2][4] = {};
  float dacc[2] = {};
  for (int rc = 0; rc < 4; ++rc) {
    __syncthreads();
#pragma unroll
    for (int i = 0; i < 4; ++i) {
      int flat = t + i * 256;
      int row = flat >> 4, c4 = (flat & 15) * 4;
      float4 w = *(const float4*)&Wrm[(rc * 64 + row) * 64 + c4];
      wT[c4 + 0][row] = w.x; wT[c4 + 1][row] = w.y;
      wT[c4 + 2][row] = w.z; wT[c4 + 3][row] = w.w;
      *(float4*)&kvL[row][c4] =
          *(const float4*)&kv[(size_t)(rc * 64 + row) * 64 + c4];
    }
    if (t < 64) denL[t] = dv[rc * 64 + t];
    __syncthreads();
    float p0[4] = {}, p1[4] = {};
#pragma unroll 8
    for (int kk = 0; kk < 64; ++kk) {
      float q0 = qT[kk][2 * ng], q1 = qT[kk][2 * ng + 1];
      float4 w4 = *(const float4*)&wT[kk][4 * rg];
      p0[0] = fmaf(q0, w4.x, p0[0]); p0[1] = fmaf(q0, w4.y, p0[1]);
      p0[2] = fmaf(q0, w4.z, p0[2]); p0[3] = fmaf(q0, w4.w, p0[3]);
      p1[0] = fmaf(q1, w4.x, p1[0]); p1[1] = fmaf(q1, w4.y, p1[1]);
      p1[2] = fmaf(q1, w4.z, p1[2]); p1[3] = fmaf(q1, w4.w, p1[3]);
    }
    {
      float ns0 = nsq[2 * ng], ns1 = nsq[2 * ng + 1];
      float4 f0, f1;
      f0.x = __expf(p0[0] - ns0) * 0.0625f;
      f0.y = __expf(p0[1] - ns0) * 0.0625f;
      f0.z = __expf(p0[2] - ns0) * 0.0625f;
      f0.w = __expf(p0[3] - ns0) * 0.0625f;
      f1.x = __expf(p1[0] - ns1) * 0.0625f;
      f1.y = __expf(p1[1] - ns1) * 0.0625f;
      f1.z = __expf(p1[2] - ns1) * 0.0625f;
      f1.w = __expf(p1[3] - ns1) * 0.0625f;
      *(float4*)&phi[2 * ng][4 * rg] = f0;
      *(float4*)&phi[2 * ng + 1][4 * rg] = f1;
    }
    __syncthreads();
#pragma unroll 4
    for (int rl = 0; rl < 64; ++rl) {
      float pa = phi[2 * rg][rl], pb = phi[2 * rg + 1][rl];
      float4 k4 = *(const float4*)&kvL[rl][4 * ng];
      float dn = denL[rl];
      acc[0][0] = fmaf(pa, k4.x, acc[0][0]);
      acc[0][1] = fmaf(pa, k4.y, acc[0][1]);
      acc[0][2] = fmaf(pa, k4.z, acc[0][2]);
      acc[0][3] = fmaf(pa, k4.w, acc[0][3]);
      acc[1][0] = fmaf(pb, k4.x, acc[1][0]);
      acc[1][1] = fmaf(pb, k4.y, acc[1][1]);
      acc[1][2] = fmaf(pb, k4.z, acc[1][2]);
      acc[1][3] = fmaf(pb, k4.w, acc[1][3]);
      dacc[0] = fmaf(pa, dn, dacc[0]);
      dacc[1] = fmaf(pb, dn, dacc[1]);
    }
  }
#pragma unroll
  for (int i = 0; i < 2; ++i) {
    int n = n0 + 2 * rg + i;
    float inv = 1.0f / (dacc[i] + 1e-6f);
    ushort4 u = {f2bf(acc[i][0] * inv), f2bf(acc[i][1] * inv),
                 f2bf(acc[i][2] * inv), f2bf(acc[i][3] * inv)};
    *(ushort4*)&attnb[(size_t)n * 1024 + h * 64 + 4 * ng] = u;
  }
}

}  // namespace

extern "C" void kernel_launch(void* const* d_in, const int* in_sizes, int n_in,
                              void* d_out, int out_size, void* d_ws,
                              size_t ws_size, hipStream_t stream) {
  const float *x = nullptr, *Wqkv = nullptr, *bqkv = nullptr;
  const float *Wproj = nullptr, *bproj = nullptr, *Wrm = nullptr;
  for (int i = 0; i < n_in; ++i) {
    switch (in_sizes[i]) {
      case 16777216: x     = (const float*)d_in[i]; break;
      case 3145728:  Wqkv  = (const float*)d_in[i]; break;
      case 3072:     bqkv  = (const float*)d_in[i]; break;
      case 1048576:  Wproj = (const float*)d_in[i]; break;
      case 1024:     bproj = (const float*)d_in[i]; break;
      case 16384:    Wrm   = (const float*)d_in[i]; break;
      default: break;
    }
  }
  float* out = (float*)d_out;
  float* ws = (float*)d_ws;

  if (!x || !Wqkv || !bqkv || !Wproj || !bproj || !Wrm) {
    k_sent<<<1, 1, 0, stream>>>(out, 2000.0f);
    return;
  }
  if (ws_size < WS_ELEMS * sizeof(float)) {
    k_sent<<<1, 1, 0, stream>>>(out, 1000.0f);
    return;
  }

  unsigned short* xh  = (unsigned short*)(ws + XH_OFF);
  unsigned short* xl  = (unsigned short*)(ws + XL_OFF);
  unsigned short* wh  = (unsigned short*)(ws + WH_OFF);
  unsigned short* wl  = (unsigned short*)(ws + WL_OFF);
  unsigned short* ambf = (unsigned short*)(ws + ATTNB_OFF);
  unsigned short* wph = (unsigned short*)(ws + WPH_OFF);

  // weight conversions (once)
  k_conv_split<<<3072, 256, 0, stream>>>(Wqkv, wh, wl, 786432);
  k_conv_hi<<<1024, 256, 0, stream>>>(Wproj, wph, 262144);

  for (int b = 0; b < 4; ++b) {
    const float* x_b = x + (size_t)b * 4096 * 1024;
    unsigned short* attnb_b = ambf + (size_t)b * 4194304;
    k_conv_split<<<4096, 256, 0, stream>>>(x_b, xh, xl, 1048576);
    // qkv split-bf16 MFMA GEMM -> q/k/v fp32 [h][n][d]
    k_qkv_mfma<<<dim3(24, 32), 256, 0, stream>>>(xh, xl, wh, wl, bqkv, ws);
    // phi_k -> partial KV/denom per (rc, nchunk, h)
    k_pass_a<<<dim3(4, NCHUNK, 16), 256, 0, stream>>>(ws, Wrm, ws + KVP_OFF,
                                                      ws + DPART_OFF);
    k_reduce<<<1040, 256, 0, stream>>>(ws);
    // phi_q -> normalized attn, bf16
    k_pass_b<<<dim3(128, 16), 256, 0, stream>>>(ws, Wrm, attnb_b);
  }
  // output projection for all 4 batches, bf16 MFMA -> fp32 out
  k_out_mfma<<<dim3(8, 128), 256, 0, stream>>>(ambf, wph, bproj, out);
}

// Round 7
// 588.554 us; speedup vs baseline: 4.1844x; 1.7687x over previous
//
#include <hip/hip_runtime.h>
#include <hip/hip_bf16.h>

namespace {

typedef __attribute__((ext_vector_type(8))) short short8v;   // 8 bf16
typedef __attribute__((ext_vector_type(4))) float float4v;   // 4 f32

// ---- workspace layout (float offsets) ----
constexpr size_t QKV1     = 4194304;                 // 16*4096*64 (per-batch q/k/v fp32)
constexpr size_t Q_OFF    = 0;
constexpr size_t K_OFF    = QKV1;
constexpr size_t V_OFF    = 2 * QKV1;
constexpr size_t KVP_OFF  = 3 * QKV1;                // [16 nc][16 h][256 r][64 d] f32
constexpr size_t KVP_SZ   = 16777216;
constexpr size_t DPART_OFF = KVP_OFF + KVP_SZ;       // [16 nc][16 h][256 r] f32
constexpr size_t DPART_SZ = 65536;
constexpr size_t KVT_OFF  = DPART_OFF + DPART_SZ;    // ushort [16 h][64 d][256 r]
constexpr size_t DENV_OFF = KVT_OFF + 131072;        // f32 [16 h][256 r]
constexpr size_t XH_OFF   = DENV_OFF + 4096;         // x hi (per-batch) ushort
constexpr size_t XL_OFF   = XH_OFF + 2097152;
constexpr size_t WH_OFF   = XL_OFF + 2097152;        // Wqkv hi ushort
constexpr size_t WL_OFF   = WH_OFF + 1572864;
constexpr size_t WRMH_OFF = WL_OFF + 1572864;        // Wrm hi ushort [256][64]
constexpr size_t WRML_OFF = WRMH_OFF + 8192;
constexpr size_t ATTNB_OFF = WRML_OFF + 8192;        // attn bf16 all batches
constexpr size_t WPH_OFF  = ATTNB_OFF + 8388608;     // Wproj hi ushort
constexpr size_t WS_ELEMS = WPH_OFF + 524288;        // 45,830,144 floats ~183 MB

__device__ __forceinline__ unsigned short f2bf(float f) {
  unsigned int u = __float_as_uint(f);
  u += 0x7FFFu + ((u >> 16) & 1u);                   // round-to-nearest-even
  return (unsigned short)(u >> 16);
}
__device__ __forceinline__ float bf2f(unsigned short u) {
  return __uint_as_float((unsigned)u << 16);
}

__global__ void k_sent(float* out, float v) { out[0] = v; }

// ---------------- fp32 -> bf16 hi+lo split
__global__ __launch_bounds__(256) void k_conv_split(
    const float* __restrict__ src, unsigned short* __restrict__ hi,
    unsigned short* __restrict__ lo, int n4) {
  int i = blockIdx.x * 256 + threadIdx.x;
  if (i >= n4) return;
  float4 v = *(const float4*)&src[(size_t)i * 4];
  ushort4 h, l;
  h.x = f2bf(v.x); l.x = f2bf(v.x - bf2f(h.x));
  h.y = f2bf(v.y); l.y = f2bf(v.y - bf2f(h.y));
  h.z = f2bf(v.z); l.z = f2bf(v.z - bf2f(h.z));
  h.w = f2bf(v.w); l.w = f2bf(v.w - bf2f(h.w));
  *(ushort4*)&hi[(size_t)i * 4] = h;
  *(ushort4*)&lo[(size_t)i * 4] = l;
}

__global__ __launch_bounds__(256) void k_conv_hi(
    const float* __restrict__ src, unsigned short* __restrict__ hi, int n4) {
  int i = blockIdx.x * 256 + threadIdx.x;
  if (i >= n4) return;
  float4 v = *(const float4*)&src[(size_t)i * 4];
  ushort4 h = {f2bf(v.x), f2bf(v.y), f2bf(v.z), f2bf(v.w)};
  *(ushort4*)&hi[(size_t)i * 4] = h;
}

// ---- stage [128 rows][64 k] bf16 tile via global_load_lds (verified r5) ----
__device__ __forceinline__ void stage_tile(const unsigned short* __restrict__ src,
                                           unsigned short* __restrict__ dst,
                                           int t) {
#pragma unroll
  for (int i = 0; i < 4; ++i) {
    int c = i * 256 + t;
    int row = c >> 3;
    int seg = (c & 7) ^ (row & 7);
    __builtin_amdgcn_global_load_lds(
        (const __attribute__((address_space(1))) void*)(src + (size_t)row * 1024 + seg * 8),
        (__attribute__((address_space(3))) void*)(dst + (size_t)c * 8),
        16, 0, 0);
  }
}

__device__ __forceinline__ short8v read_frag(const unsigned short* lds, int row,
                                             int seg) {
  return *(const short8v*)&lds[(size_t)row * 64 + ((seg ^ (row & 7)) * 8)];
}

// ---------------- qkv GEMM, split-bf16 (UNCHANGED, verified r5)
__global__ __launch_bounds__(256, 2) void k_qkv_mfma(
    const unsigned short* __restrict__ xh, const unsigned short* __restrict__ xl,
    const unsigned short* __restrict__ wh, const unsigned short* __restrict__ wl,
    const float* __restrict__ bq, float* __restrict__ ws) {
  __shared__ unsigned short ldsA[2][8192];
  __shared__ unsigned short ldsB[2][8192];
  const int t = threadIdx.x;
  const int lane = t & 63, wv = t >> 6;
  const int wm = wv >> 1, wn = wv & 1;
  const int lr = lane & 15, lg = lane >> 4;
  const int mBase = blockIdx.y * 128;
  const int jBase = blockIdx.x * 128;
  float4v acc[4][4];
#pragma unroll
  for (int a = 0; a < 4; ++a)
#pragma unroll
    for (int b = 0; b < 4; ++b) acc[a][b] = (float4v){0.f, 0.f, 0.f, 0.f};

  for (int kt = 0; kt < 1024; kt += 64) {
    __syncthreads();
    stage_tile(xh + (size_t)mBase * 1024 + kt, ldsA[0], t);
    stage_tile(xl + (size_t)mBase * 1024 + kt, ldsA[1], t);
    stage_tile(wh + (size_t)jBase * 1024 + kt, ldsB[0], t);
    stage_tile(wl + (size_t)jBase * 1024 + kt, ldsB[1], t);
    asm volatile("s_waitcnt vmcnt(0)");
    __syncthreads();
#pragma unroll
    for (int ks = 0; ks < 2; ++ks) {
      const int seg = ks * 4 + lg;
      short8v ah[4], al[4], bh[4], bl[4];
#pragma unroll
      for (int f = 0; f < 4; ++f) {
        int ra = wm * 64 + f * 16 + lr;
        ah[f] = read_frag(ldsA[0], ra, seg);
        al[f] = read_frag(ldsA[1], ra, seg);
        int rb = wn * 64 + f * 16 + lr;
        bh[f] = read_frag(ldsB[0], rb, seg);
        bl[f] = read_frag(ldsB[1], rb, seg);
      }
#pragma unroll
      for (int fm = 0; fm < 4; ++fm)
#pragma unroll
        for (int fn = 0; fn < 4; ++fn) {
          acc[fm][fn] = __builtin_amdgcn_mfma_f32_16x16x32_bf16(
              ah[fm], bh[fn], acc[fm][fn], 0, 0, 0);
          acc[fm][fn] = __builtin_amdgcn_mfma_f32_16x16x32_bf16(
              ah[fm], bl[fn], acc[fm][fn], 0, 0, 0);
          acc[fm][fn] = __builtin_amdgcn_mfma_f32_16x16x32_bf16(
              al[fm], bh[fn], acc[fm][fn], 0, 0, 0);
        }
    }
  }
#pragma unroll
  for (int fn = 0; fn < 4; ++fn) {
    int j = jBase + wn * 64 + fn * 16 + lr;
    int t3 = j >> 10, h = (j >> 6) & 15, dd = j & 63;
    float bias = bq[j];
    float* op = ws + (size_t)t3 * QKV1 + (size_t)h * 262144 + dd;
#pragma unroll
    for (int fm = 0; fm < 4; ++fm) {
      int n0 = mBase + wm * 64 + fm * 16 + lg * 4;
#pragma unroll
      for (int r = 0; r < 4; ++r)
        op[(size_t)(n0 + r) * 64] = acc[fm][fn][r] + bias;
    }
  }
}

// ---------------- pass A: fused phi_k (split-bf16 MFMA) + KV MFMA accumulate
__global__ __launch_bounds__(256) void k_pass_a_mfma(
    const float* __restrict__ ws, const unsigned short* __restrict__ wrmh,
    const unsigned short* __restrict__ wrml, float* __restrict__ kvp,
    float* __restrict__ dpart) {
  __shared__ __align__(16) unsigned short khi[32][72];  // FIX: was [32][40], cols go to 63
  __shared__ __align__(16) unsigned short klo[32][72];  // FIX
  __shared__ __align__(16) unsigned short vT[64][40];   // v^T [d][n<=31] OK
  __shared__ __align__(16) unsigned short phL[256][40]; // phi^T [r][n<=31] OK
  __shared__ __align__(16) float nsL[32];
  const int t = threadIdx.x;
  const int lane = t & 63, wv = t >> 6;
  const int lr = lane & 15, lg = lane >> 4;
  const int nc = blockIdx.x, h = blockIdx.y;
  const float* kb = ws + K_OFF + (size_t)h * 262144;
  const float* vb = ws + V_OFF + (size_t)h * 262144;
  float4v acc[4][4];      // KV[r=wv*64+rf*16+lg*4+i][d=df*16+lr]
#pragma unroll
  for (int a = 0; a < 4; ++a)
#pragma unroll
    for (int b = 0; b < 4; ++b) acc[a][b] = (float4v){0.f, 0.f, 0.f, 0.f};
  float dacc[4] = {};

  for (int tile = 0; tile < 8; ++tile) {
    const int n0 = nc * 256 + tile * 32;
    __syncthreads();
    {  // stage k hi/lo + ns ; n = t>>3, d-run = (t&7)*8
      int sn = t >> 3, sd = (t & 7) * 8;
      const float* kp = kb + (size_t)(n0 + sn) * 64 + sd;
      float4 a0 = *(const float4*)kp;
      float4 a1 = *(const float4*)(kp + 4);
      float vv[8] = {a0.x, a0.y, a0.z, a0.w, a1.x, a1.y, a1.z, a1.w};
      short8v hv, lv;
      float ss = 0.f;
#pragma unroll
      for (int j = 0; j < 8; ++j) {
        ss += vv[j] * vv[j];
        unsigned short hu = f2bf(vv[j]);
        hv[j] = (short)hu;
        lv[j] = (short)f2bf(vv[j] - bf2f(hu));
      }
      *(short8v*)&khi[sn][sd] = hv;
      *(short8v*)&klo[sn][sd] = lv;
      ss += __shfl_xor(ss, 1); ss += __shfl_xor(ss, 2); ss += __shfl_xor(ss, 4);
      if ((t & 7) == 0) nsL[sn] = 0.5f * ss;
    }
    {  // stage v transposed ; n = t&31, d-run = (t>>5)*8
      int sn = t & 31, sd = (t >> 5) * 8;
      const float* vp = vb + (size_t)(n0 + sn) * 64 + sd;
      float4 a0 = *(const float4*)vp;
      float4 a1 = *(const float4*)(vp + 4);
      float vv[8] = {a0.x, a0.y, a0.z, a0.w, a1.x, a1.y, a1.z, a1.w};
#pragma unroll
      for (int j = 0; j < 8; ++j) vT[sd + j][sn] = f2bf(vv[j]);
    }
    __syncthreads();
    // proj P[n, r] = k . wrm  (split 3-MFMA); waves split r (64 each)
    float4v p[2][4];
#pragma unroll
    for (int a = 0; a < 2; ++a)
#pragma unroll
      for (int b = 0; b < 4; ++b) p[a][b] = (float4v){0.f, 0.f, 0.f, 0.f};
#pragma unroll
    for (int ks = 0; ks < 2; ++ks) {
      short8v ah[2], al[2];
#pragma unroll
      for (int nf = 0; nf < 2; ++nf) {
        ah[nf] = *(const short8v*)&khi[nf * 16 + lr][ks * 32 + lg * 8];
        al[nf] = *(const short8v*)&klo[nf * 16 + lr][ks * 32 + lg * 8];
      }
#pragma unroll
      for (int rf = 0; rf < 4; ++rf) {
        size_t wo = (size_t)(wv * 64 + rf * 16 + lr) * 64 + ks * 32 + lg * 8;
        short8v bh = *(const short8v*)&wrmh[wo];
        short8v bl = *(const short8v*)&wrml[wo];
#pragma unroll
        for (int nf = 0; nf < 2; ++nf) {
          p[nf][rf] = __builtin_amdgcn_mfma_f32_16x16x32_bf16(ah[nf], bh, p[nf][rf], 0, 0, 0);
          p[nf][rf] = __builtin_amdgcn_mfma_f32_16x16x32_bf16(ah[nf], bl, p[nf][rf], 0, 0, 0);
          p[nf][rf] = __builtin_amdgcn_mfma_f32_16x16x32_bf16(al[nf], bh, p[nf][rf], 0, 0, 0);
        }
      }
    }
    // exp -> phi bf16 -> phL ; den partials (rounded phi, consistent)
#pragma unroll
    for (int nf = 0; nf < 2; ++nf) {
      float4 ns4 = *(const float4*)&nsL[nf * 16 + lg * 4];
      float nsa[4] = {ns4.x, ns4.y, ns4.z, ns4.w};
#pragma unroll
      for (int rf = 0; rf < 4; ++rf) {
        ushort4 u;
        float s = 0.f;
        unsigned short uu;
        uu = f2bf(__expf(p[nf][rf][0] - nsa[0]) * 0.0625f); u.x = uu; s += bf2f(uu);
        uu = f2bf(__expf(p[nf][rf][1] - nsa[1]) * 0.0625f); u.y = uu; s += bf2f(uu);
        uu = f2bf(__expf(p[nf][rf][2] - nsa[2]) * 0.0625f); u.z = uu; s += bf2f(uu);
        uu = f2bf(__expf(p[nf][rf][3] - nsa[3]) * 0.0625f); u.w = uu; s += bf2f(uu);
        dacc[rf] += s;
        *(ushort4*)&phL[wv * 64 + rf * 16 + lr][nf * 16 + lg * 4] = u;
      }
    }
    // KV += phi^T @ v  (K = 32 over n); wave-local phL rows
    {
      short8v af[4], bf_[4];
#pragma unroll
      for (int rf = 0; rf < 4; ++rf)
        af[rf] = *(const short8v*)&phL[wv * 64 + rf * 16 + lr][lg * 8];
#pragma unroll
      for (int df = 0; df < 4; ++df)
        bf_[df] = *(const short8v*)&vT[df * 16 + lr][lg * 8];
#pragma unroll
      for (int rf = 0; rf < 4; ++rf)
#pragma unroll
        for (int df = 0; df < 4; ++df)
          acc[rf][df] = __builtin_amdgcn_mfma_f32_16x16x32_bf16(
              af[rf], bf_[df], acc[rf][df], 0, 0, 0);
    }
  }
  // write partials
  size_t rbase = ((size_t)nc * 16 + h) * 256;
#pragma unroll
  for (int rf = 0; rf < 4; ++rf) {
#pragma unroll
    for (int df = 0; df < 4; ++df)
#pragma unroll
      for (int i = 0; i < 4; ++i) {
        int r = wv * 64 + rf * 16 + lg * 4 + i;
        kvp[(rbase + r) * 64 + df * 16 + lr] = acc[rf][df][i];
      }
    float dv2 = dacc[rf];
    dv2 += __shfl_xor(dv2, 16);
    dv2 += __shfl_xor(dv2, 32);
    if (lg == 0) dpart[rbase + wv * 64 + rf * 16 + lr] = dv2;
  }
}

// ---------------- reduce partials -> KV^T bf16 [h][d][r] + denv f32
__global__ __launch_bounds__(256) void k_reduce_t(
    const float* __restrict__ kvp, const float* __restrict__ dpart,
    unsigned short* __restrict__ kvt, float* __restrict__ denv) {
  __shared__ __align__(16) float tile[32][69];
  const int rb = blockIdx.x, h = blockIdx.y;   // rb 0..7 (32 r each)
  const int t = threadIdx.x;
  const int rl = t >> 3, sd = (t & 7) * 8;
  float s[8] = {};
  for (int c = 0; c < 16; ++c) {
    const float* p = kvp + ((size_t)(c * 16 + h) * 256 + rb * 32 + rl) * 64 + sd;
    float4 b0 = *(const float4*)p, b1 = *(const float4*)(p + 4);
    s[0] += b0.x; s[1] += b0.y; s[2] += b0.z; s[3] += b0.w;
    s[4] += b1.x; s[5] += b1.y; s[6] += b1.z; s[7] += b1.w;
  }
#pragma unroll
  for (int j = 0; j < 8; ++j) tile[rl][sd + j] = s[j];
  __syncthreads();
  int d = t >> 2, rj = (t & 3) * 8;
  short8v u;
#pragma unroll
  for (int j = 0; j < 8; ++j) u[j] = (short)f2bf(tile[rj + j][d]);
  *(short8v*)&kvt[((size_t)h * 64 + d) * 256 + rb * 32 + rj] = u;
  if (rb == 0) {
    float sum = 0.f;
    for (int c = 0; c < 16; ++c)
      sum += dpart[(size_t)(c * 16 + h) * 256 + t];
    denv[h * 256 + t] = sum;
  }
}

// ---------------- pass B: fused phi_q (split MFMA) + PV MFMA + normalize
__global__ __launch_bounds__(256) void k_pass_b_mfma(
    const float* __restrict__ ws, const unsigned short* __restrict__ wrmh,
    const unsigned short* __restrict__ wrml,
    const unsigned short* __restrict__ kvt, const float* __restrict__ denv,
    unsigned short* __restrict__ attnb) {
  __shared__ __align__(16) unsigned short kvL[64][264];  // KV^T [d][r]
  __shared__ __align__(16) unsigned short phL[32][264];  // phi [n][r]
  __shared__ __align__(16) unsigned short qhi[32][72];   // FIX: was [32][40]
  __shared__ __align__(16) unsigned short qlo[32][72];   // FIX
  __shared__ __align__(16) unsigned short outL[32][80];
  __shared__ __align__(16) float denvL[256];
  __shared__ __align__(16) float nsL[32];
  __shared__ float denp[4][32];
  __shared__ float invL[32];
  const int t = threadIdx.x;
  const int lane = t & 63, wv = t >> 6;
  const int lr = lane & 15, lg = lane >> 4;
  const int nc = blockIdx.x, h = blockIdx.y;
  const float* qb = ws + Q_OFF + (size_t)h * 262144;
  {  // load KV^T + denv once
    const unsigned short* src = kvt + (size_t)h * 16384 + (size_t)t * 64;
    int d = t >> 2, r0 = (t & 3) * 64;
#pragma unroll
    for (int j = 0; j < 8; ++j)
      *(short8v*)&kvL[d][r0 + j * 8] = *(const short8v*)(src + j * 8);
    denvL[t] = denv[h * 256 + t];
  }
  for (int tile = 0; tile < 8; ++tile) {
    const int n0 = nc * 256 + tile * 32;
    __syncthreads();
    {  // stage q hi/lo + ns
      int sn = t >> 3, sd = (t & 7) * 8;
      const float* qp = qb + (size_t)(n0 + sn) * 64 + sd;
      float4 a0 = *(const float4*)qp;
      float4 a1 = *(const float4*)(qp + 4);
      float vv[8] = {a0.x, a0.y, a0.z, a0.w, a1.x, a1.y, a1.z, a1.w};
      short8v hv, lv;
      float ss = 0.f;
#pragma unroll
      for (int j = 0; j < 8; ++j) {
        ss += vv[j] * vv[j];
        unsigned short hu = f2bf(vv[j]);
        hv[j] = (short)hu;
        lv[j] = (short)f2bf(vv[j] - bf2f(hu));
      }
      *(short8v*)&qhi[sn][sd] = hv;
      *(short8v*)&qlo[sn][sd] = lv;
      ss += __shfl_xor(ss, 1); ss += __shfl_xor(ss, 2); ss += __shfl_xor(ss, 4);
      if ((t & 7) == 0) nsL[sn] = 0.5f * ss;
    }
    __syncthreads();
    // proj: A = wrm rows r (M-side), B = q rows n (col-side); D[r, n]
    float4v p[4][2];
#pragma unroll
    for (int a = 0; a < 4; ++a)
#pragma unroll
      for (int b = 0; b < 2; ++b) p[a][b] = (float4v){0.f, 0.f, 0.f, 0.f};
#pragma unroll
    for (int ks = 0; ks < 2; ++ks) {
      short8v bh[2], bl[2];
#pragma unroll
      for (int nf = 0; nf < 2; ++nf) {
        bh[nf] = *(const short8v*)&qhi[nf * 16 + lr][ks * 32 + lg * 8];
        bl[nf] = *(const short8v*)&qlo[nf * 16 + lr][ks * 32 + lg * 8];
      }
#pragma unroll
      for (int rf = 0; rf < 4; ++rf) {
        size_t wo = (size_t)(wv * 64 + rf * 16 + lr) * 64 + ks * 32 + lg * 8;
        short8v ah = *(const short8v*)&wrmh[wo];
        short8v al = *(const short8v*)&wrml[wo];
#pragma unroll
        for (int nf = 0; nf < 2; ++nf) {
          p[rf][nf] = __builtin_amdgcn_mfma_f32_16x16x32_bf16(ah, bh[nf], p[rf][nf], 0, 0, 0);
          p[rf][nf] = __builtin_amdgcn_mfma_f32_16x16x32_bf16(al, bh[nf], p[rf][nf], 0, 0, 0);
          p[rf][nf] = __builtin_amdgcn_mfma_f32_16x16x32_bf16(ah, bl[nf], p[rf][nf], 0, 0, 0);
        }
      }
    }
    // exp -> phi bf16 -> phL[n][r]; den[n] partial = sum_r phi*denv
    float dnp[2] = {0.f, 0.f};
#pragma unroll
    for (int nf = 0; nf < 2; ++nf) {
      float ns = nsL[nf * 16 + lr];
#pragma unroll
      for (int rf = 0; rf < 4; ++rf) {
        float4 dv4 = *(const float4*)&denvL[wv * 64 + rf * 16 + lg * 4];
        float da[4] = {dv4.x, dv4.y, dv4.z, dv4.w};
        ushort4 u;
        unsigned short uu;
        float s = 0.f;
        uu = f2bf(__expf(p[rf][nf][0] - ns) * 0.0625f); u.x = uu; s += bf2f(uu) * da[0];
        uu = f2bf(__expf(p[rf][nf][1] - ns) * 0.0625f); u.y = uu; s += bf2f(uu) * da[1];
        uu = f2bf(__expf(p[rf][nf][2] - ns) * 0.0625f); u.z = uu; s += bf2f(uu) * da[2];
        uu = f2bf(__expf(p[rf][nf][3] - ns) * 0.0625f); u.w = uu; s += bf2f(uu) * da[3];
        dnp[nf] += s;
        *(ushort4*)&phL[nf * 16 + lr][wv * 64 + rf * 16 + lg * 4] = u;
      }
    }
#pragma unroll
    for (int nf = 0; nf < 2; ++nf) {
      float v2 = dnp[nf];
      v2 += __shfl_xor(v2, 16);
      v2 += __shfl_xor(v2, 32);
      if (lg == 0) denp[wv][nf * 16 + lr] = v2;
    }
    __syncthreads();
    if (t < 32) {
      float dn = denp[0][t] + denp[1][t] + denp[2][t] + denp[3][t];
      invL[t] = 1.0f / (dn + 1e-6f);
    }
    __syncthreads();
    // O = phi @ KV^T ; wave -> (nfj = wv&1, df pair = (wv>>1)*2+{0,1}), K=256
    const int nfj = wv & 1;
    float4v o[2];
    o[0] = (float4v){0.f, 0.f, 0.f, 0.f};
    o[1] = (float4v){0.f, 0.f, 0.f, 0.f};
#pragma unroll
    for (int ks = 0; ks < 8; ++ks) {
      short8v af = *(const short8v*)&phL[nfj * 16 + lr][ks * 32 + lg * 8];
#pragma unroll
      for (int j = 0; j < 2; ++j) {
        int df = (wv >> 1) * 2 + j;
        short8v bfr = *(const short8v*)&kvL[df * 16 + lr][ks * 32 + lg * 8];
        o[j] = __builtin_amdgcn_mfma_f32_16x16x32_bf16(af, bfr, o[j], 0, 0, 0);
      }
    }
#pragma unroll
    for (int j = 0; j < 2; ++j) {
      int df = (wv >> 1) * 2 + j;
#pragma unroll
      for (int i = 0; i < 4; ++i) {
        int n = nfj * 16 + lg * 4 + i;
        outL[n][df * 16 + lr] = f2bf(o[j][i] * invL[n]);
      }
    }
    __syncthreads();
    {  // coalesced bf16 store
      int sn = t >> 3, sd = (t & 7) * 8;
      short8v v8 = *(const short8v*)&outL[sn][sd];
      *(short8v*)&attnb[((size_t)(n0 + sn)) * 1024 + h * 64 + sd] = v8;
    }
  }
}

// ---------------- out GEMM (UNCHANGED, verified r5)
__global__ __launch_bounds__(256, 2) void k_out_mfma(
    const unsigned short* __restrict__ ab, const unsigned short* __restrict__ wp,
    const float* __restrict__ bp, float* __restrict__ out) {
  __shared__ unsigned short ldsA[8192];
  __shared__ unsigned short ldsB[8192];
  const int t = threadIdx.x;
  const int lane = t & 63, wv = t >> 6;
  const int wm = wv >> 1, wn = wv & 1;
  const int lr = lane & 15, lg = lane >> 4;
  const int mBase = blockIdx.y * 128;
  const int jBase = blockIdx.x * 128;
  float4v acc[4][4];
#pragma unroll
  for (int a = 0; a < 4; ++a)
#pragma unroll
    for (int b = 0; b < 4; ++b) acc[a][b] = (float4v){0.f, 0.f, 0.f, 0.f};

  for (int kt = 0; kt < 1024; kt += 64) {
    __syncthreads();
    stage_tile(ab + (size_t)mBase * 1024 + kt, ldsA, t);
    stage_tile(wp + (size_t)jBase * 1024 + kt, ldsB, t);
    asm volatile("s_waitcnt vmcnt(0)");
    __syncthreads();
#pragma unroll
    for (int ks = 0; ks < 2; ++ks) {
      const int seg = ks * 4 + lg;
      short8v a[4], b[4];
#pragma unroll
      for (int f = 0; f < 4; ++f) {
        a[f] = read_frag(ldsA, wm * 64 + f * 16 + lr, seg);
        b[f] = read_frag(ldsB, wn * 64 + f * 16 + lr, seg);
      }
#pragma unroll
      for (int fm = 0; fm < 4; ++fm)
#pragma unroll
        for (int fn = 0; fn < 4; ++fn)
          acc[fm][fn] = __builtin_amdgcn_mfma_f32_16x16x32_bf16(
              a[fm], b[fn], acc[fm][fn], 0, 0, 0);
    }
  }
#pragma unroll
  for (int fn = 0; fn < 4; ++fn) {
    int j = jBase + wn * 64 + fn * 16 + lr;
    float bias = bp[j];
#pragma unroll
    for (int fm = 0; fm < 4; ++fm) {
      int m0 = mBase + wm * 64 + fm * 16 + lg * 4;
#pragma unroll
      for (int r = 0; r < 4; ++r)
        out[(size_t)(m0 + r) * 1024 + j] = acc[fm][fn][r] + bias;
    }
  }
}

}  // namespace

extern "C" void kernel_launch(void* const* d_in, const int* in_sizes, int n_in,
                              void* d_out, int out_size, void* d_ws,
                              size_t ws_size, hipStream_t stream) {
  const float *x = nullptr, *Wqkv = nullptr, *bqkv = nullptr;
  const float *Wproj = nullptr, *bproj = nullptr, *Wrm = nullptr;
  for (int i = 0; i < n_in; ++i) {
    switch (in_sizes[i]) {
      case 16777216: x     = (const float*)d_in[i]; break;
      case 3145728:  Wqkv  = (const float*)d_in[i]; break;
      case 3072:     bqkv  = (const float*)d_in[i]; break;
      case 1048576:  Wproj = (const float*)d_in[i]; break;
      case 1024:     bproj = (const float*)d_in[i]; break;
      case 16384:    Wrm   = (const float*)d_in[i]; break;
      default: break;
    }
  }
  float* out = (float*)d_out;
  float* ws = (float*)d_ws;

  if (!x || !Wqkv || !bqkv || !Wproj || !bproj || !Wrm) {
    k_sent<<<1, 1, 0, stream>>>(out, 2000.0f);
    return;
  }
  if (ws_size < WS_ELEMS * sizeof(float)) {
    k_sent<<<1, 1, 0, stream>>>(out, 1000.0f);
    return;
  }

  unsigned short* xh   = (unsigned short*)(ws + XH_OFF);
  unsigned short* xl   = (unsigned short*)(ws + XL_OFF);
  unsigned short* wh   = (unsigned short*)(ws + WH_OFF);
  unsigned short* wl   = (unsigned short*)(ws + WL_OFF);
  unsigned short* wrmh = (unsigned short*)(ws + WRMH_OFF);
  unsigned short* wrml = (unsigned short*)(ws + WRML_OFF);
  unsigned short* ambf = (unsigned short*)(ws + ATTNB_OFF);
  unsigned short* wph  = (unsigned short*)(ws + WPH_OFF);
  unsigned short* kvt  = (unsigned short*)(ws + KVT_OFF);

  k_conv_split<<<3072, 256, 0, stream>>>(Wqkv, wh, wl, 786432);
  k_conv_split<<<16, 256, 0, stream>>>(Wrm, wrmh, wrml, 4096);
  k_conv_hi<<<1024, 256, 0, stream>>>(Wproj, wph, 262144);

  for (int b = 0; b < 4; ++b) {
    const float* x_b = x + (size_t)b * 4096 * 1024;
    unsigned short* attnb_b = ambf + (size_t)b * 4194304;
    k_conv_split<<<4096, 256, 0, stream>>>(x_b, xh, xl, 1048576);
    k_qkv_mfma<<<dim3(24, 32), 256, 0, stream>>>(xh, xl, wh, wl, bqkv, ws);
    k_pass_a_mfma<<<dim3(16, 16), 256, 0, stream>>>(ws, wrmh, wrml,
                                                    ws + KVP_OFF, ws + DPART_OFF);
    k_reduce_t<<<dim3(8, 16), 256, 0, stream>>>(ws + KVP_OFF, ws + DPART_OFF,
                                                kvt, ws + DENV_OFF);
    k_pass_b_mfma<<<dim3(16, 16), 256, 0, stream>>>(ws, wrmh, wrml, kvt,
                                                    ws + DENV_OFF, attnb_b);
  }
  k_out_mfma<<<dim3(8, 128), 256, 0, stream>>>(ambf, wph, bproj, out);
}

// Round 8
// 543.718 us; speedup vs baseline: 4.5294x; 1.0825x over previous
//
#include <hip/hip_runtime.h>
#include <hip/hip_bf16.h>

namespace {

typedef __attribute__((ext_vector_type(8))) short short8v;   // 8 bf16
typedef __attribute__((ext_vector_type(4))) float float4v;   // 4 f32

// ---- workspace layout (float offsets) ----
constexpr size_t QKV1     = 4194304;                 // 16*4096*64
constexpr size_t Q_OFF    = 0;
constexpr size_t K_OFF    = QKV1;
constexpr size_t VB_OFF   = 2 * QKV1;                // v as bf16 ushort [16h][4096n][64d]
constexpr size_t KVP_OFF  = 3 * QKV1;                // [16 nc][16 h][256 r][64 d] f32
constexpr size_t KVP_SZ   = 16777216;
constexpr size_t DPART_OFF = KVP_OFF + KVP_SZ;       // [16 nc][16 h][256 r] f32
constexpr size_t DPART_SZ = 65536;
constexpr size_t KVT_OFF  = DPART_OFF + DPART_SZ;    // ushort [16 h][64 d][256 r]
constexpr size_t DENV_OFF = KVT_OFF + 131072;        // f32 [16 h][256 r]
constexpr size_t XH_OFF   = DENV_OFF + 4096;         // x hi (per-batch) ushort
constexpr size_t XL_OFF   = XH_OFF + 2097152;
constexpr size_t WH_OFF   = XL_OFF + 2097152;        // Wqkv hi ushort
constexpr size_t WL_OFF   = WH_OFF + 1572864;
constexpr size_t WRMH_OFF = WL_OFF + 1572864;        // Wrm hi ushort [256][64]
constexpr size_t WRML_OFF = WRMH_OFF + 8192;
constexpr size_t ATTNB_OFF = WRML_OFF + 8192;        // attn bf16 all batches
constexpr size_t WPH_OFF  = ATTNB_OFF + 8388608;     // Wproj hi ushort
constexpr size_t WS_ELEMS = WPH_OFF + 524288;        // ~183 MB

__device__ __forceinline__ unsigned short f2bf(float f) {
  unsigned int u = __float_as_uint(f);
  u += 0x7FFFu + ((u >> 16) & 1u);                   // round-to-nearest-even
  return (unsigned short)(u >> 16);
}
__device__ __forceinline__ float bf2f(unsigned short u) {
  return __uint_as_float((unsigned)u << 16);
}

__global__ void k_sent(float* out, float v) { out[0] = v; }

// ---------------- fp32 -> bf16 hi+lo split
__global__ __launch_bounds__(256) void k_conv_split(
    const float* __restrict__ src, unsigned short* __restrict__ hi,
    unsigned short* __restrict__ lo, int n4) {
  int i = blockIdx.x * 256 + threadIdx.x;
  if (i >= n4) return;
  float4 v = *(const float4*)&src[(size_t)i * 4];
  ushort4 h, l;
  h.x = f2bf(v.x); l.x = f2bf(v.x - bf2f(h.x));
  h.y = f2bf(v.y); l.y = f2bf(v.y - bf2f(h.y));
  h.z = f2bf(v.z); l.z = f2bf(v.z - bf2f(h.z));
  h.w = f2bf(v.w); l.w = f2bf(v.w - bf2f(h.w));
  *(ushort4*)&hi[(size_t)i * 4] = h;
  *(ushort4*)&lo[(size_t)i * 4] = l;
}

__global__ __launch_bounds__(256) void k_conv_hi(
    const float* __restrict__ src, unsigned short* __restrict__ hi, int n4) {
  int i = blockIdx.x * 256 + threadIdx.x;
  if (i >= n4) return;
  float4 v = *(const float4*)&src[(size_t)i * 4];
  ushort4 h = {f2bf(v.x), f2bf(v.y), f2bf(v.z), f2bf(v.w)};
  *(ushort4*)&hi[(size_t)i * 4] = h;
}

// ---- stage [128 rows][64 k] bf16 tile via global_load_lds (verified) ----
__device__ __forceinline__ void stage_tile(const unsigned short* __restrict__ src,
                                           unsigned short* __restrict__ dst,
                                           int t) {
#pragma unroll
  for (int i = 0; i < 4; ++i) {
    int c = i * 256 + t;
    int row = c >> 3;
    int seg = (c & 7) ^ (row & 7);
    __builtin_amdgcn_global_load_lds(
        (const __attribute__((address_space(1))) void*)(src + (size_t)row * 1024 + seg * 8),
        (__attribute__((address_space(3))) void*)(dst + (size_t)c * 8),
        16, 0, 0);
  }
}

__device__ __forceinline__ short8v read_frag(const unsigned short* lds, int row,
                                             int seg) {
  return *(const short8v*)&lds[(size_t)row * 64 + ((seg ^ (row & 7)) * 8)];
}

// ---------------- qkv GEMM for q/k columns (j<2048), split-bf16 (verified)
__global__ __launch_bounds__(256, 2) void k_qkv_mfma(
    const unsigned short* __restrict__ xh, const unsigned short* __restrict__ xl,
    const unsigned short* __restrict__ wh, const unsigned short* __restrict__ wl,
    const float* __restrict__ bq, float* __restrict__ ws) {
  __shared__ unsigned short ldsA[2][8192];
  __shared__ unsigned short ldsB[2][8192];
  const int t = threadIdx.x;
  const int lane = t & 63, wv = t >> 6;
  const int wm = wv >> 1, wn = wv & 1;
  const int lr = lane & 15, lg = lane >> 4;
  const int mBase = blockIdx.y * 128;
  const int jBase = blockIdx.x * 128;           // < 2048 (q/k region only)
  float4v acc[4][4];
#pragma unroll
  for (int a = 0; a < 4; ++a)
#pragma unroll
    for (int b = 0; b < 4; ++b) acc[a][b] = (float4v){0.f, 0.f, 0.f, 0.f};

  for (int kt = 0; kt < 1024; kt += 64) {
    __syncthreads();
    stage_tile(xh + (size_t)mBase * 1024 + kt, ldsA[0], t);
    stage_tile(xl + (size_t)mBase * 1024 + kt, ldsA[1], t);
    stage_tile(wh + (size_t)jBase * 1024 + kt, ldsB[0], t);
    stage_tile(wl + (size_t)jBase * 1024 + kt, ldsB[1], t);
    asm volatile("s_waitcnt vmcnt(0)");
    __syncthreads();
#pragma unroll
    for (int ks = 0; ks < 2; ++ks) {
      const int seg = ks * 4 + lg;
      short8v ah[4], al[4], bh[4], bl[4];
#pragma unroll
      for (int f = 0; f < 4; ++f) {
        int ra = wm * 64 + f * 16 + lr;
        ah[f] = read_frag(ldsA[0], ra, seg);
        al[f] = read_frag(ldsA[1], ra, seg);
        int rb = wn * 64 + f * 16 + lr;
        bh[f] = read_frag(ldsB[0], rb, seg);
        bl[f] = read_frag(ldsB[1], rb, seg);
      }
#pragma unroll
      for (int fm = 0; fm < 4; ++fm)
#pragma unroll
        for (int fn = 0; fn < 4; ++fn) {
          acc[fm][fn] = __builtin_amdgcn_mfma_f32_16x16x32_bf16(
              ah[fm], bh[fn], acc[fm][fn], 0, 0, 0);
          acc[fm][fn] = __builtin_amdgcn_mfma_f32_16x16x32_bf16(
              ah[fm], bl[fn], acc[fm][fn], 0, 0, 0);
          acc[fm][fn] = __builtin_amdgcn_mfma_f32_16x16x32_bf16(
              al[fm], bh[fn], acc[fm][fn], 0, 0, 0);
        }
    }
  }
#pragma unroll
  for (int fn = 0; fn < 4; ++fn) {
    int j = jBase + wn * 64 + fn * 16 + lr;
    int t3 = j >> 10, h = (j >> 6) & 15, dd = j & 63;   // t3 in {0,1}
    float bias = bq[j];
    float* op = ws + (size_t)t3 * QKV1 + (size_t)h * 262144 + dd;
#pragma unroll
    for (int fm = 0; fm < 4; ++fm) {
      int n0 = mBase + wm * 64 + fm * 16 + lg * 4;
#pragma unroll
      for (int r = 0; r < 4; ++r)
        op[(size_t)(n0 + r) * 64] = acc[fm][fn][r] + bias;
    }
  }
}

// ---------------- qkv GEMM for v columns (j in [2048,3072)), plain bf16 -> bf16 v
__global__ __launch_bounds__(256, 2) void k_qkv_v(
    const unsigned short* __restrict__ xh, const unsigned short* __restrict__ wh,
    const float* __restrict__ bq, unsigned short* __restrict__ vb) {
  __shared__ unsigned short ldsA[8192];
  __shared__ unsigned short ldsB[8192];
  const int t = threadIdx.x;
  const int lane = t & 63, wv = t >> 6;
  const int wm = wv >> 1, wn = wv & 1;
  const int lr = lane & 15, lg = lane >> 4;
  const int mBase = blockIdx.y * 128;
  const int jBase = 2048 + blockIdx.x * 128;
  float4v acc[4][4];
#pragma unroll
  for (int a = 0; a < 4; ++a)
#pragma unroll
    for (int b = 0; b < 4; ++b) acc[a][b] = (float4v){0.f, 0.f, 0.f, 0.f};

  for (int kt = 0; kt < 1024; kt += 64) {
    __syncthreads();
    stage_tile(xh + (size_t)mBase * 1024 + kt, ldsA, t);
    stage_tile(wh + (size_t)jBase * 1024 + kt, ldsB, t);
    asm volatile("s_waitcnt vmcnt(0)");
    __syncthreads();
#pragma unroll
    for (int ks = 0; ks < 2; ++ks) {
      const int seg = ks * 4 + lg;
      short8v a[4], b[4];
#pragma unroll
      for (int f = 0; f < 4; ++f) {
        a[f] = read_frag(ldsA, wm * 64 + f * 16 + lr, seg);
        b[f] = read_frag(ldsB, wn * 64 + f * 16 + lr, seg);
      }
#pragma unroll
      for (int fm = 0; fm < 4; ++fm)
#pragma unroll
        for (int fn = 0; fn < 4; ++fn)
          acc[fm][fn] = __builtin_amdgcn_mfma_f32_16x16x32_bf16(
              a[fm], b[fn], acc[fm][fn], 0, 0, 0);
    }
  }
#pragma unroll
  for (int fn = 0; fn < 4; ++fn) {
    int j = jBase + wn * 64 + fn * 16 + lr;
    int h = (j >> 6) & 15, dd = j & 63;
    float bias = bq[j];
    unsigned short* op = vb + (size_t)h * 262144 + dd;
#pragma unroll
    for (int fm = 0; fm < 4; ++fm) {
      int n0 = mBase + wm * 64 + fm * 16 + lg * 4;
#pragma unroll
      for (int r = 0; r < 4; ++r)
        op[(size_t)(n0 + r) * 64] = f2bf(acc[fm][fn][r] + bias);
    }
  }
}

// ---------------- pass A: fused phi_k (split MFMA) + KV MFMA accumulate
__global__ __launch_bounds__(256) void k_pass_a_mfma(
    const float* __restrict__ ws, const unsigned short* __restrict__ vbb,
    const unsigned short* __restrict__ wrmh,
    const unsigned short* __restrict__ wrml, float* __restrict__ kvp,
    float* __restrict__ dpart) {
  __shared__ __align__(16) unsigned short khi[32][72];
  __shared__ __align__(16) unsigned short klo[32][72];
  __shared__ __align__(16) unsigned short vT[64][40];   // v^T [d][n<=31]
  __shared__ __align__(16) unsigned short phL[256][40]; // phi^T [r][n<=31]
  __shared__ __align__(16) float nsL[32];
  const int t = threadIdx.x;
  const int lane = t & 63, wv = t >> 6;
  const int lr = lane & 15, lg = lane >> 4;
  const int nc = blockIdx.x, h = blockIdx.y;
  const float* kb = ws + K_OFF + (size_t)h * 262144;
  const unsigned short* vbh = vbb + (size_t)h * 262144;
  float4v acc[4][4];
#pragma unroll
  for (int a = 0; a < 4; ++a)
#pragma unroll
    for (int b = 0; b < 4; ++b) acc[a][b] = (float4v){0.f, 0.f, 0.f, 0.f};
  float dacc[4] = {};

  for (int tile = 0; tile < 8; ++tile) {
    const int n0 = nc * 256 + tile * 32;
    __syncthreads();
    {  // stage k hi/lo + ns
      int sn = t >> 3, sd = (t & 7) * 8;
      const float* kp = kb + (size_t)(n0 + sn) * 64 + sd;
      float4 a0 = *(const float4*)kp;
      float4 a1 = *(const float4*)(kp + 4);
      float vv[8] = {a0.x, a0.y, a0.z, a0.w, a1.x, a1.y, a1.z, a1.w};
      short8v hv, lv;
      float ss = 0.f;
#pragma unroll
      for (int j = 0; j < 8; ++j) {
        ss += vv[j] * vv[j];
        unsigned short hu = f2bf(vv[j]);
        hv[j] = (short)hu;
        lv[j] = (short)f2bf(vv[j] - bf2f(hu));
      }
      *(short8v*)&khi[sn][sd] = hv;
      *(short8v*)&klo[sn][sd] = lv;
      ss += __shfl_xor(ss, 1); ss += __shfl_xor(ss, 2); ss += __shfl_xor(ss, 4);
      if ((t & 7) == 0) nsL[sn] = 0.5f * ss;
    }
    {  // stage v (already bf16) transposed
      int sn = t & 31, sd = (t >> 5) * 8;
      short8v v8 = *(const short8v*)&vbh[(size_t)(n0 + sn) * 64 + sd];
#pragma unroll
      for (int j = 0; j < 8; ++j) vT[sd + j][sn] = (unsigned short)v8[j];
    }
    __syncthreads();
    // proj P[n, r] = k . wrm (split 3-MFMA); waves split r
    float4v p[2][4];
#pragma unroll
    for (int a = 0; a < 2; ++a)
#pragma unroll
      for (int b = 0; b < 4; ++b) p[a][b] = (float4v){0.f, 0.f, 0.f, 0.f};
#pragma unroll
    for (int ks = 0; ks < 2; ++ks) {
      short8v ah[2], al[2];
#pragma unroll
      for (int nf = 0; nf < 2; ++nf) {
        ah[nf] = *(const short8v*)&khi[nf * 16 + lr][ks * 32 + lg * 8];
        al[nf] = *(const short8v*)&klo[nf * 16 + lr][ks * 32 + lg * 8];
      }
#pragma unroll
      for (int rf = 0; rf < 4; ++rf) {
        size_t wo = (size_t)(wv * 64 + rf * 16 + lr) * 64 + ks * 32 + lg * 8;
        short8v bh = *(const short8v*)&wrmh[wo];
        short8v bl = *(const short8v*)&wrml[wo];
#pragma unroll
        for (int nf = 0; nf < 2; ++nf) {
          p[nf][rf] = __builtin_amdgcn_mfma_f32_16x16x32_bf16(ah[nf], bh, p[nf][rf], 0, 0, 0);
          p[nf][rf] = __builtin_amdgcn_mfma_f32_16x16x32_bf16(ah[nf], bl, p[nf][rf], 0, 0, 0);
          p[nf][rf] = __builtin_amdgcn_mfma_f32_16x16x32_bf16(al[nf], bh, p[nf][rf], 0, 0, 0);
        }
      }
    }
#pragma unroll
    for (int nf = 0; nf < 2; ++nf) {
      float4 ns4 = *(const float4*)&nsL[nf * 16 + lg * 4];
      float nsa[4] = {ns4.x, ns4.y, ns4.z, ns4.w};
#pragma unroll
      for (int rf = 0; rf < 4; ++rf) {
        ushort4 u;
        float s = 0.f;
        unsigned short uu;
        uu = f2bf(__expf(p[nf][rf][0] - nsa[0]) * 0.0625f); u.x = uu; s += bf2f(uu);
        uu = f2bf(__expf(p[nf][rf][1] - nsa[1]) * 0.0625f); u.y = uu; s += bf2f(uu);
        uu = f2bf(__expf(p[nf][rf][2] - nsa[2]) * 0.0625f); u.z = uu; s += bf2f(uu);
        uu = f2bf(__expf(p[nf][rf][3] - nsa[3]) * 0.0625f); u.w = uu; s += bf2f(uu);
        dacc[rf] += s;
        *(ushort4*)&phL[wv * 64 + rf * 16 + lr][nf * 16 + lg * 4] = u;
      }
    }
    {
      short8v af[4], bf_[4];
#pragma unroll
      for (int rf = 0; rf < 4; ++rf)
        af[rf] = *(const short8v*)&phL[wv * 64 + rf * 16 + lr][lg * 8];
#pragma unroll
      for (int df = 0; df < 4; ++df)
        bf_[df] = *(const short8v*)&vT[df * 16 + lr][lg * 8];
#pragma unroll
      for (int rf = 0; rf < 4; ++rf)
#pragma unroll
        for (int df = 0; df < 4; ++df)
          acc[rf][df] = __builtin_amdgcn_mfma_f32_16x16x32_bf16(
              af[rf], bf_[df], acc[rf][df], 0, 0, 0);
    }
  }
  size_t rbase = ((size_t)nc * 16 + h) * 256;
#pragma unroll
  for (int rf = 0; rf < 4; ++rf) {
#pragma unroll
    for (int df = 0; df < 4; ++df)
#pragma unroll
      for (int i = 0; i < 4; ++i) {
        int r = wv * 64 + rf * 16 + lg * 4 + i;
        kvp[(rbase + r) * 64 + df * 16 + lr] = acc[rf][df][i];
      }
    float dv2 = dacc[rf];
    dv2 += __shfl_xor(dv2, 16);
    dv2 += __shfl_xor(dv2, 32);
    if (lg == 0) dpart[rbase + wv * 64 + rf * 16 + lr] = dv2;
  }
}

// ---------------- reduce partials -> KV^T bf16 [h][d][r] + denv f32
__global__ __launch_bounds__(256) void k_reduce_t(
    const float* __restrict__ kvp, const float* __restrict__ dpart,
    unsigned short* __restrict__ kvt, float* __restrict__ denv) {
  __shared__ __align__(16) float tile[32][69];
  const int rb = blockIdx.x, h = blockIdx.y;
  const int t = threadIdx.x;
  const int rl = t >> 3, sd = (t & 7) * 8;
  float s[8] = {};
  for (int c = 0; c < 16; ++c) {
    const float* p = kvp + ((size_t)(c * 16 + h) * 256 + rb * 32 + rl) * 64 + sd;
    float4 b0 = *(const float4*)p, b1 = *(const float4*)(p + 4);
    s[0] += b0.x; s[1] += b0.y; s[2] += b0.z; s[3] += b0.w;
    s[4] += b1.x; s[5] += b1.y; s[6] += b1.z; s[7] += b1.w;
  }
#pragma unroll
  for (int j = 0; j < 8; ++j) tile[rl][sd + j] = s[j];
  __syncthreads();
  int d = t >> 2, rj = (t & 3) * 8;
  short8v u;
#pragma unroll
  for (int j = 0; j < 8; ++j) u[j] = (short)f2bf(tile[rj + j][d]);
  *(short8v*)&kvt[((size_t)h * 64 + d) * 256 + rb * 32 + rj] = u;
  if (rb == 0) {
    float sum = 0.f;
    for (int c = 0; c < 16; ++c)
      sum += dpart[(size_t)(c * 16 + h) * 256 + t];
    denv[h * 256 + t] = sum;
  }
}

// ---------------- pass B: fused phi_q (split MFMA) + PV MFMA + normalize
__global__ __launch_bounds__(256) void k_pass_b_mfma(
    const float* __restrict__ ws, const unsigned short* __restrict__ wrmh,
    const unsigned short* __restrict__ wrml,
    const unsigned short* __restrict__ kvt, const float* __restrict__ denv,
    unsigned short* __restrict__ attnb) {
  __shared__ __align__(16) unsigned short kvL[64][264];
  __shared__ __align__(16) unsigned short phL[32][264];
  __shared__ __align__(16) unsigned short qhi[32][72];
  __shared__ __align__(16) unsigned short qlo[32][72];
  __shared__ __align__(16) unsigned short outL[32][80];
  __shared__ __align__(16) float denvL[256];
  __shared__ __align__(16) float nsL[32];
  __shared__ float denp[4][32];
  __shared__ float invL[32];
  const int t = threadIdx.x;
  const int lane = t & 63, wv = t >> 6;
  const int lr = lane & 15, lg = lane >> 4;
  const int nc = blockIdx.x, h = blockIdx.y;   // nc 0..31, 128 rows each
  const float* qb = ws + Q_OFF + (size_t)h * 262144;
  {
    const unsigned short* src = kvt + (size_t)h * 16384 + (size_t)t * 64;
    int d = t >> 2, r0 = (t & 3) * 64;
#pragma unroll
    for (int j = 0; j < 8; ++j)
      *(short8v*)&kvL[d][r0 + j * 8] = *(const short8v*)(src + j * 8);
    denvL[t] = denv[h * 256 + t];
  }
  for (int tile = 0; tile < 4; ++tile) {
    const int n0 = nc * 128 + tile * 32;
    __syncthreads();
    {  // stage q hi/lo + ns
      int sn = t >> 3, sd = (t & 7) * 8;
      const float* qp = qb + (size_t)(n0 + sn) * 64 + sd;
      float4 a0 = *(const float4*)qp;
      float4 a1 = *(const float4*)(qp + 4);
      float vv[8] = {a0.x, a0.y, a0.z, a0.w, a1.x, a1.y, a1.z, a1.w};
      short8v hv, lv;
      float ss = 0.f;
#pragma unroll
      for (int j = 0; j < 8; ++j) {
        ss += vv[j] * vv[j];
        unsigned short hu = f2bf(vv[j]);
        hv[j] = (short)hu;
        lv[j] = (short)f2bf(vv[j] - bf2f(hu));
      }
      *(short8v*)&qhi[sn][sd] = hv;
      *(short8v*)&qlo[sn][sd] = lv;
      ss += __shfl_xor(ss, 1); ss += __shfl_xor(ss, 2); ss += __shfl_xor(ss, 4);
      if ((t & 7) == 0) nsL[sn] = 0.5f * ss;
    }
    __syncthreads();
    float4v p[4][2];
#pragma unroll
    for (int a = 0; a < 4; ++a)
#pragma unroll
      for (int b = 0; b < 2; ++b) p[a][b] = (float4v){0.f, 0.f, 0.f, 0.f};
#pragma unroll
    for (int ks = 0; ks < 2; ++ks) {
      short8v bh[2], bl[2];
#pragma unroll
      for (int nf = 0; nf < 2; ++nf) {
        bh[nf] = *(const short8v*)&qhi[nf * 16 + lr][ks * 32 + lg * 8];
        bl[nf] = *(const short8v*)&qlo[nf * 16 + lr][ks * 32 + lg * 8];
      }
#pragma unroll
      for (int rf = 0; rf < 4; ++rf) {
        size_t wo = (size_t)(wv * 64 + rf * 16 + lr) * 64 + ks * 32 + lg * 8;
        short8v ah = *(const short8v*)&wrmh[wo];
        short8v al = *(const short8v*)&wrml[wo];
#pragma unroll
        for (int nf = 0; nf < 2; ++nf) {
          p[rf][nf] = __builtin_amdgcn_mfma_f32_16x16x32_bf16(ah, bh[nf], p[rf][nf], 0, 0, 0);
          p[rf][nf] = __builtin_amdgcn_mfma_f32_16x16x32_bf16(al, bh[nf], p[rf][nf], 0, 0, 0);
          p[rf][nf] = __builtin_amdgcn_mfma_f32_16x16x32_bf16(ah, bl[nf], p[rf][nf], 0, 0, 0);
        }
      }
    }
    float dnp[2] = {0.f, 0.f};
#pragma unroll
    for (int nf = 0; nf < 2; ++nf) {
      float ns = nsL[nf * 16 + lr];
#pragma unroll
      for (int rf = 0; rf < 4; ++rf) {
        float4 dv4 = *(const float4*)&denvL[wv * 64 + rf * 16 + lg * 4];
        float da[4] = {dv4.x, dv4.y, dv4.z, dv4.w};
        ushort4 u;
        unsigned short uu;
        float s = 0.f;
        uu = f2bf(__expf(p[rf][nf][0] - ns) * 0.0625f); u.x = uu; s += bf2f(uu) * da[0];
        uu = f2bf(__expf(p[rf][nf][1] - ns) * 0.0625f); u.y = uu; s += bf2f(uu) * da[1];
        uu = f2bf(__expf(p[rf][nf][2] - ns) * 0.0625f); u.z = uu; s += bf2f(uu) * da[2];
        uu = f2bf(__expf(p[rf][nf][3] - ns) * 0.0625f); u.w = uu; s += bf2f(uu) * da[3];
        dnp[nf] += s;
        *(ushort4*)&phL[nf * 16 + lr][wv * 64 + rf * 16 + lg * 4] = u;
      }
    }
#pragma unroll
    for (int nf = 0; nf < 2; ++nf) {
      float v2 = dnp[nf];
      v2 += __shfl_xor(v2, 16);
      v2 += __shfl_xor(v2, 32);
      if (lg == 0) denp[wv][nf * 16 + lr] = v2;
    }
    __syncthreads();
    if (t < 32) {
      float dn = denp[0][t] + denp[1][t] + denp[2][t] + denp[3][t];
      invL[t] = 1.0f / (dn + 1e-6f);
    }
    __syncthreads();
    const int nfj = wv & 1;
    float4v o[2];
    o[0] = (float4v){0.f, 0.f, 0.f, 0.f};
    o[1] = (float4v){0.f, 0.f, 0.f, 0.f};
#pragma unroll
    for (int ks = 0; ks < 8; ++ks) {
      short8v af = *(const short8v*)&phL[nfj * 16 + lr][ks * 32 + lg * 8];
#pragma unroll
      for (int j = 0; j < 2; ++j) {
        int df = (wv >> 1) * 2 + j;
        short8v bfr = *(const short8v*)&kvL[df * 16 + lr][ks * 32 + lg * 8];
        o[j] = __builtin_amdgcn_mfma_f32_16x16x32_bf16(af, bfr, o[j], 0, 0, 0);
      }
    }
#pragma unroll
    for (int j = 0; j < 2; ++j) {
      int df = (wv >> 1) * 2 + j;
#pragma unroll
      for (int i = 0; i < 4; ++i) {
        int n = nfj * 16 + lg * 4 + i;
        outL[n][df * 16 + lr] = f2bf(o[j][i] * invL[n]);
      }
    }
    __syncthreads();
    {
      int sn = t >> 3, sd = (t & 7) * 8;
      short8v v8 = *(const short8v*)&outL[sn][sd];
      *(short8v*)&attnb[((size_t)(n0 + sn)) * 1024 + h * 64 + sd] = v8;
    }
  }
}

// ---------------- out GEMM (verified)
__global__ __launch_bounds__(256, 2) void k_out_mfma(
    const unsigned short* __restrict__ ab, const unsigned short* __restrict__ wp,
    const float* __restrict__ bp, float* __restrict__ out) {
  __shared__ unsigned short ldsA[8192];
  __shared__ unsigned short ldsB[8192];
  const int t = threadIdx.x;
  const int lane = t & 63, wv = t >> 6;
  const int wm = wv >> 1, wn = wv & 1;
  const int lr = lane & 15, lg = lane >> 4;
  const int mBase = blockIdx.y * 128;
  const int jBase = blockIdx.x * 128;
  float4v acc[4][4];
#pragma unroll
  for (int a = 0; a < 4; ++a)
#pragma unroll
    for (int b = 0; b < 4; ++b) acc[a][b] = (float4v){0.f, 0.f, 0.f, 0.f};

  for (int kt = 0; kt < 1024; kt += 64) {
    __syncthreads();
    stage_tile(ab + (size_t)mBase * 1024 + kt, ldsA, t);
    stage_tile(wp + (size_t)jBase * 1024 + kt, ldsB, t);
    asm volatile("s_waitcnt vmcnt(0)");
    __syncthreads();
#pragma unroll
    for (int ks = 0; ks < 2; ++ks) {
      const int seg = ks * 4 + lg;
      short8v a[4], b[4];
#pragma unroll
      for (int f = 0; f < 4; ++f) {
        a[f] = read_frag(ldsA, wm * 64 + f * 16 + lr, seg);
        b[f] = read_frag(ldsB, wn * 64 + f * 16 + lr, seg);
      }
#pragma unroll
      for (int fm = 0; fm < 4; ++fm)
#pragma unroll
        for (int fn = 0; fn < 4; ++fn)
          acc[fm][fn] = __builtin_amdgcn_mfma_f32_16x16x32_bf16(
              a[fm], b[fn], acc[fm][fn], 0, 0, 0);
    }
  }
#pragma unroll
  for (int fn = 0; fn < 4; ++fn) {
    int j = jBase + wn * 64 + fn * 16 + lr;
    float bias = bp[j];
#pragma unroll
    for (int fm = 0; fm < 4; ++fm) {
      int m0 = mBase + wm * 64 + fm * 16 + lg * 4;
#pragma unroll
      for (int r = 0; r < 4; ++r)
        out[(size_t)(m0 + r) * 1024 + j] = acc[fm][fn][r] + bias;
    }
  }
}

}  // namespace

extern "C" void kernel_launch(void* const* d_in, const int* in_sizes, int n_in,
                              void* d_out, int out_size, void* d_ws,
                              size_t ws_size, hipStream_t stream) {
  const float *x = nullptr, *Wqkv = nullptr, *bqkv = nullptr;
  const float *Wproj = nullptr, *bproj = nullptr, *Wrm = nullptr;
  for (int i = 0; i < n_in; ++i) {
    switch (in_sizes[i]) {
      case 16777216: x     = (const float*)d_in[i]; break;
      case 3145728:  Wqkv  = (const float*)d_in[i]; break;
      case 3072:     bqkv  = (const float*)d_in[i]; break;
      case 1048576:  Wproj = (const float*)d_in[i]; break;
      case 1024:     bproj = (const float*)d_in[i]; break;
      case 16384:    Wrm   = (const float*)d_in[i]; break;
      default: break;
    }
  }
  float* out = (float*)d_out;
  float* ws = (float*)d_ws;

  if (!x || !Wqkv || !bqkv || !Wproj || !bproj || !Wrm) {
    k_sent<<<1, 1, 0, stream>>>(out, 2000.0f);
    return;
  }
  if (ws_size < WS_ELEMS * sizeof(float)) {
    k_sent<<<1, 1, 0, stream>>>(out, 1000.0f);
    return;
  }

  unsigned short* xh   = (unsigned short*)(ws + XH_OFF);
  unsigned short* xl   = (unsigned short*)(ws + XL_OFF);
  unsigned short* wh   = (unsigned short*)(ws + WH_OFF);
  unsigned short* wl   = (unsigned short*)(ws + WL_OFF);
  unsigned short* wrmh = (unsigned short*)(ws + WRMH_OFF);
  unsigned short* wrml = (unsigned short*)(ws + WRML_OFF);
  unsigned short* ambf = (unsigned short*)(ws + ATTNB_OFF);
  unsigned short* wph  = (unsigned short*)(ws + WPH_OFF);
  unsigned short* kvt  = (unsigned short*)(ws + KVT_OFF);
  unsigned short* vb   = (unsigned short*)(ws + VB_OFF);

  k_conv_split<<<3072, 256, 0, stream>>>(Wqkv, wh, wl, 786432);
  k_conv_split<<<16, 256, 0, stream>>>(Wrm, wrmh, wrml, 4096);
  k_conv_hi<<<1024, 256, 0, stream>>>(Wproj, wph, 262144);

  for (int b = 0; b < 4; ++b) {
    const float* x_b = x + (size_t)b * 4096 * 1024;
    unsigned short* attnb_b = ambf + (size_t)b * 4194304;
    k_conv_split<<<4096, 256, 0, stream>>>(x_b, xh, xl, 1048576);
    // q/k columns: split-bf16 (j<2048); v columns: plain bf16 -> vb
    k_qkv_mfma<<<dim3(16, 32), 256, 0, stream>>>(xh, xl, wh, wl, bqkv, ws);
    k_qkv_v<<<dim3(8, 32), 256, 0, stream>>>(xh, wh, bqkv, vb);
    k_pass_a_mfma<<<dim3(16, 16), 256, 0, stream>>>(ws, vb, wrmh, wrml,
                                                    ws + KVP_OFF, ws + DPART_OFF);
    k_reduce_t<<<dim3(8, 16), 256, 0, stream>>>(ws + KVP_OFF, ws + DPART_OFF,
                                                kvt, ws + DENV_OFF);
    k_pass_b_mfma<<<dim3(32, 16), 256, 0, stream>>>(ws, wrmh, wrml, kvt,
                                                    ws + DENV_OFF, attnb_b);
  }
  k_out_mfma<<<dim3(8, 128), 256, 0, stream>>>(ambf, wph, bproj, out);
}

// Round 9
// 475.047 us; speedup vs baseline: 5.1842x; 1.1446x over previous
//
#include <hip/hip_runtime.h>
#include <hip/hip_bf16.h>

namespace {

typedef __attribute__((ext_vector_type(8))) short short8v;   // 8 bf16
typedef __attribute__((ext_vector_type(4))) float float4v;   // 4 f32

// ---- workspace layout (float offsets) ----
constexpr size_t QKV1     = 4194304;                 // 16*4096*64
constexpr size_t Q_OFF    = 0;
constexpr size_t K_OFF    = QKV1;
constexpr size_t VB_OFF   = 2 * QKV1;                // v bf16 ushort [16h][4096n][64d]
constexpr size_t KVP_OFF  = 3 * QKV1;                // bf16 partials [16nc][16h][256r][64d]
constexpr size_t KVP_SZ   = 16777216;                // (allocated as float-slots; used as ushort)
constexpr size_t DPART_OFF = KVP_OFF + KVP_SZ;       // [16 nc][16 h][256 r] f32
constexpr size_t DPART_SZ = 65536;
constexpr size_t KVT_OFF  = DPART_OFF + DPART_SZ;    // ushort [16 h][64 d][256 r]
constexpr size_t DENV_OFF = KVT_OFF + 131072;        // f32 [16 h][256 r]
constexpr size_t XH_OFF   = DENV_OFF + 4096;         // x hi (per-batch) ushort
constexpr size_t XL_OFF   = XH_OFF + 2097152;        // (unused now)
constexpr size_t WH_OFF   = XL_OFF + 2097152;        // Wqkv hi ushort
constexpr size_t WL_OFF   = WH_OFF + 1572864;
constexpr size_t WRMH_OFF = WL_OFF + 1572864;        // Wrm hi ushort [256][64]
constexpr size_t WRML_OFF = WRMH_OFF + 8192;
constexpr size_t ATTNB_OFF = WRML_OFF + 8192;        // attn bf16 all batches
constexpr size_t WPH_OFF  = ATTNB_OFF + 8388608;     // Wproj hi ushort
constexpr size_t WS_ELEMS = WPH_OFF + 524288;        // ~183 MB

__device__ __forceinline__ unsigned short f2bf(float f) {
  unsigned int u = __float_as_uint(f);
  u += 0x7FFFu + ((u >> 16) & 1u);                   // round-to-nearest-even
  return (unsigned short)(u >> 16);
}
__device__ __forceinline__ float bf2f(unsigned short u) {
  return __uint_as_float((unsigned)u << 16);
}

__global__ void k_sent(float* out, float v) { out[0] = v; }

// ---------------- fp32 -> bf16 hi+lo split (weights)
__global__ __launch_bounds__(256) void k_conv_split(
    const float* __restrict__ src, unsigned short* __restrict__ hi,
    unsigned short* __restrict__ lo, int n4) {
  int i = blockIdx.x * 256 + threadIdx.x;
  if (i >= n4) return;
  float4 v = *(const float4*)&src[(size_t)i * 4];
  ushort4 h, l;
  h.x = f2bf(v.x); l.x = f2bf(v.x - bf2f(h.x));
  h.y = f2bf(v.y); l.y = f2bf(v.y - bf2f(h.y));
  h.z = f2bf(v.z); l.z = f2bf(v.z - bf2f(h.z));
  h.w = f2bf(v.w); l.w = f2bf(v.w - bf2f(h.w));
  *(ushort4*)&hi[(size_t)i * 4] = h;
  *(ushort4*)&lo[(size_t)i * 4] = l;
}

__global__ __launch_bounds__(256) void k_conv_hi(
    const float* __restrict__ src, unsigned short* __restrict__ hi, int n4) {
  int i = blockIdx.x * 256 + threadIdx.x;
  if (i >= n4) return;
  float4 v = *(const float4*)&src[(size_t)i * 4];
  ushort4 h = {f2bf(v.x), f2bf(v.y), f2bf(v.z), f2bf(v.w)};
  *(ushort4*)&hi[(size_t)i * 4] = h;
}

// ---- stage [128 rows][64 k] bf16 tile via global_load_lds (verified) ----
__device__ __forceinline__ void stage_tile(const unsigned short* __restrict__ src,
                                           unsigned short* __restrict__ dst,
                                           int t) {
#pragma unroll
  for (int i = 0; i < 4; ++i) {
    int c = i * 256 + t;
    int row = c >> 3;
    int seg = (c & 7) ^ (row & 7);
    __builtin_amdgcn_global_load_lds(
        (const __attribute__((address_space(1))) void*)(src + (size_t)row * 1024 + seg * 8),
        (__attribute__((address_space(3))) void*)(dst + (size_t)c * 8),
        16, 0, 0);
  }
}

__device__ __forceinline__ short8v read_frag(const unsigned short* lds, int row,
                                             int seg) {
  return *(const short8v*)&lds[(size_t)row * 64 + ((seg ^ (row & 7)) * 8)];
}

// ---------------- qkv GEMM q/k (j<2048): 2-MFMA (xh@wh + xh@wl; xl dropped)
__global__ __launch_bounds__(256, 2) void k_qkv_mfma(
    const unsigned short* __restrict__ xh,
    const unsigned short* __restrict__ wh, const unsigned short* __restrict__ wl,
    const float* __restrict__ bq, float* __restrict__ ws) {
  __shared__ unsigned short ldsA[8192];
  __shared__ unsigned short ldsB[2][8192];
  const int t = threadIdx.x;
  const int lane = t & 63, wv = t >> 6;
  const int wm = wv >> 1, wn = wv & 1;
  const int lr = lane & 15, lg = lane >> 4;
  const int mBase = blockIdx.y * 128;
  const int jBase = blockIdx.x * 128;           // < 2048 (q/k region only)
  float4v acc[4][4];
#pragma unroll
  for (int a = 0; a < 4; ++a)
#pragma unroll
    for (int b = 0; b < 4; ++b) acc[a][b] = (float4v){0.f, 0.f, 0.f, 0.f};

  for (int kt = 0; kt < 1024; kt += 64) {
    __syncthreads();
    stage_tile(xh + (size_t)mBase * 1024 + kt, ldsA, t);
    stage_tile(wh + (size_t)jBase * 1024 + kt, ldsB[0], t);
    stage_tile(wl + (size_t)jBase * 1024 + kt, ldsB[1], t);
    asm volatile("s_waitcnt vmcnt(0)");
    __syncthreads();
#pragma unroll
    for (int ks = 0; ks < 2; ++ks) {
      const int seg = ks * 4 + lg;
      short8v ah[4], bh[4], bl[4];
#pragma unroll
      for (int f = 0; f < 4; ++f) {
        ah[f] = read_frag(ldsA, wm * 64 + f * 16 + lr, seg);
        int rb = wn * 64 + f * 16 + lr;
        bh[f] = read_frag(ldsB[0], rb, seg);
        bl[f] = read_frag(ldsB[1], rb, seg);
      }
#pragma unroll
      for (int fm = 0; fm < 4; ++fm)
#pragma unroll
        for (int fn = 0; fn < 4; ++fn) {
          acc[fm][fn] = __builtin_amdgcn_mfma_f32_16x16x32_bf16(
              ah[fm], bh[fn], acc[fm][fn], 0, 0, 0);
          acc[fm][fn] = __builtin_amdgcn_mfma_f32_16x16x32_bf16(
              ah[fm], bl[fn], acc[fm][fn], 0, 0, 0);
        }
    }
  }
#pragma unroll
  for (int fn = 0; fn < 4; ++fn) {
    int j = jBase + wn * 64 + fn * 16 + lr;
    int t3 = j >> 10, h = (j >> 6) & 15, dd = j & 63;   // t3 in {0,1}
    float bias = bq[j];
    float* op = ws + (size_t)t3 * QKV1 + (size_t)h * 262144 + dd;
#pragma unroll
    for (int fm = 0; fm < 4; ++fm) {
      int n0 = mBase + wm * 64 + fm * 16 + lg * 4;
#pragma unroll
      for (int r = 0; r < 4; ++r)
        op[(size_t)(n0 + r) * 64] = acc[fm][fn][r] + bias;
    }
  }
}

// ---------------- qkv GEMM v columns (j in [2048,3072)), plain bf16 -> bf16 v
__global__ __launch_bounds__(256, 2) void k_qkv_v(
    const unsigned short* __restrict__ xh, const unsigned short* __restrict__ wh,
    const float* __restrict__ bq, unsigned short* __restrict__ vb) {
  __shared__ unsigned short ldsA[8192];
  __shared__ unsigned short ldsB[8192];
  const int t = threadIdx.x;
  const int lane = t & 63, wv = t >> 6;
  const int wm = wv >> 1, wn = wv & 1;
  const int lr = lane & 15, lg = lane >> 4;
  const int mBase = blockIdx.y * 128;
  const int jBase = 2048 + blockIdx.x * 128;
  float4v acc[4][4];
#pragma unroll
  for (int a = 0; a < 4; ++a)
#pragma unroll
    for (int b = 0; b < 4; ++b) acc[a][b] = (float4v){0.f, 0.f, 0.f, 0.f};

  for (int kt = 0; kt < 1024; kt += 64) {
    __syncthreads();
    stage_tile(xh + (size_t)mBase * 1024 + kt, ldsA, t);
    stage_tile(wh + (size_t)jBase * 1024 + kt, ldsB, t);
    asm volatile("s_waitcnt vmcnt(0)");
    __syncthreads();
#pragma unroll
    for (int ks = 0; ks < 2; ++ks) {
      const int seg = ks * 4 + lg;
      short8v a[4], b[4];
#pragma unroll
      for (int f = 0; f < 4; ++f) {
        a[f] = read_frag(ldsA, wm * 64 + f * 16 + lr, seg);
        b[f] = read_frag(ldsB, wn * 64 + f * 16 + lr, seg);
      }
#pragma unroll
      for (int fm = 0; fm < 4; ++fm)
#pragma unroll
        for (int fn = 0; fn < 4; ++fn)
          acc[fm][fn] = __builtin_amdgcn_mfma_f32_16x16x32_bf16(
              a[fm], b[fn], acc[fm][fn], 0, 0, 0);
    }
  }
#pragma unroll
  for (int fn = 0; fn < 4; ++fn) {
    int j = jBase + wn * 64 + fn * 16 + lr;
    int h = (j >> 6) & 15, dd = j & 63;
    float bias = bq[j];
    unsigned short* op = vb + (size_t)h * 262144 + dd;
#pragma unroll
    for (int fm = 0; fm < 4; ++fm) {
      int n0 = mBase + wm * 64 + fm * 16 + lg * 4;
#pragma unroll
      for (int r = 0; r < 4; ++r)
        op[(size_t)(n0 + r) * 64] = f2bf(acc[fm][fn][r] + bias);
    }
  }
}

// ---------------- pass A: fused phi_k (split MFMA) + KV MFMA accumulate
__global__ __launch_bounds__(256) void k_pass_a_mfma(
    const float* __restrict__ ws, const unsigned short* __restrict__ vbb,
    const unsigned short* __restrict__ wrmh,
    const unsigned short* __restrict__ wrml, unsigned short* __restrict__ kvp,
    float* __restrict__ dpart) {
  __shared__ __align__(16) unsigned short khi[32][72];
  __shared__ __align__(16) unsigned short klo[32][72];
  __shared__ __align__(16) unsigned short vT[64][40];   // v^T [d][n<=31]
  __shared__ __align__(16) unsigned short phL[256][40]; // phi^T [r][n<=31]
  __shared__ __align__(16) float nsL[32];
  const int t = threadIdx.x;
  const int lane = t & 63, wv = t >> 6;
  const int lr = lane & 15, lg = lane >> 4;
  const int nc = blockIdx.x, h = blockIdx.y;
  const float* kb = ws + K_OFF + (size_t)h * 262144;
  const unsigned short* vbh = vbb + (size_t)h * 262144;
  float4v acc[4][4];
#pragma unroll
  for (int a = 0; a < 4; ++a)
#pragma unroll
    for (int b = 0; b < 4; ++b) acc[a][b] = (float4v){0.f, 0.f, 0.f, 0.f};
  float dacc[4] = {};

  for (int tile = 0; tile < 8; ++tile) {
    const int n0 = nc * 256 + tile * 32;
    __syncthreads();
    {  // stage k hi/lo + ns
      int sn = t >> 3, sd = (t & 7) * 8;
      const float* kp = kb + (size_t)(n0 + sn) * 64 + sd;
      float4 a0 = *(const float4*)kp;
      float4 a1 = *(const float4*)(kp + 4);
      float vv[8] = {a0.x, a0.y, a0.z, a0.w, a1.x, a1.y, a1.z, a1.w};
      short8v hv, lv;
      float ss = 0.f;
#pragma unroll
      for (int j = 0; j < 8; ++j) {
        ss += vv[j] * vv[j];
        unsigned short hu = f2bf(vv[j]);
        hv[j] = (short)hu;
        lv[j] = (short)f2bf(vv[j] - bf2f(hu));
      }
      *(short8v*)&khi[sn][sd] = hv;
      *(short8v*)&klo[sn][sd] = lv;
      ss += __shfl_xor(ss, 1); ss += __shfl_xor(ss, 2); ss += __shfl_xor(ss, 4);
      if ((t & 7) == 0) nsL[sn] = 0.5f * ss;
    }
    {  // stage v (bf16) transposed
      int sn = t & 31, sd = (t >> 5) * 8;
      short8v v8 = *(const short8v*)&vbh[(size_t)(n0 + sn) * 64 + sd];
#pragma unroll
      for (int j = 0; j < 8; ++j) vT[sd + j][sn] = (unsigned short)v8[j];
    }
    __syncthreads();
    // proj P[n, r] = k . wrm (split 3-MFMA); waves split r
    float4v p[2][4];
#pragma unroll
    for (int a = 0; a < 2; ++a)
#pragma unroll
      for (int b = 0; b < 4; ++b) p[a][b] = (float4v){0.f, 0.f, 0.f, 0.f};
#pragma unroll
    for (int ks = 0; ks < 2; ++ks) {
      short8v ah[2], al[2];
#pragma unroll
      for (int nf = 0; nf < 2; ++nf) {
        ah[nf] = *(const short8v*)&khi[nf * 16 + lr][ks * 32 + lg * 8];
        al[nf] = *(const short8v*)&klo[nf * 16 + lr][ks * 32 + lg * 8];
      }
#pragma unroll
      for (int rf = 0; rf < 4; ++rf) {
        size_t wo = (size_t)(wv * 64 + rf * 16 + lr) * 64 + ks * 32 + lg * 8;
        short8v bh = *(const short8v*)&wrmh[wo];
        short8v bl = *(const short8v*)&wrml[wo];
#pragma unroll
        for (int nf = 0; nf < 2; ++nf) {
          p[nf][rf] = __builtin_amdgcn_mfma_f32_16x16x32_bf16(ah[nf], bh, p[nf][rf], 0, 0, 0);
          p[nf][rf] = __builtin_amdgcn_mfma_f32_16x16x32_bf16(ah[nf], bl, p[nf][rf], 0, 0, 0);
          p[nf][rf] = __builtin_amdgcn_mfma_f32_16x16x32_bf16(al[nf], bh, p[nf][rf], 0, 0, 0);
        }
      }
    }
#pragma unroll
    for (int nf = 0; nf < 2; ++nf) {
      float4 ns4 = *(const float4*)&nsL[nf * 16 + lg * 4];
      float nsa[4] = {ns4.x, ns4.y, ns4.z, ns4.w};
#pragma unroll
      for (int rf = 0; rf < 4; ++rf) {
        ushort4 u;
        float s = 0.f;
        unsigned short uu;
        uu = f2bf(__expf(p[nf][rf][0] - nsa[0]) * 0.0625f); u.x = uu; s += bf2f(uu);
        uu = f2bf(__expf(p[nf][rf][1] - nsa[1]) * 0.0625f); u.y = uu; s += bf2f(uu);
        uu = f2bf(__expf(p[nf][rf][2] - nsa[2]) * 0.0625f); u.z = uu; s += bf2f(uu);
        uu = f2bf(__expf(p[nf][rf][3] - nsa[3]) * 0.0625f); u.w = uu; s += bf2f(uu);
        dacc[rf] += s;
        *(ushort4*)&phL[wv * 64 + rf * 16 + lr][nf * 16 + lg * 4] = u;
      }
    }
    {
      short8v af[4], bf_[4];
#pragma unroll
      for (int rf = 0; rf < 4; ++rf)
        af[rf] = *(const short8v*)&phL[wv * 64 + rf * 16 + lr][lg * 8];
#pragma unroll
      for (int df = 0; df < 4; ++df)
        bf_[df] = *(const short8v*)&vT[df * 16 + lr][lg * 8];
#pragma unroll
      for (int rf = 0; rf < 4; ++rf)
#pragma unroll
        for (int df = 0; df < 4; ++df)
          acc[rf][df] = __builtin_amdgcn_mfma_f32_16x16x32_bf16(
              af[rf], bf_[df], acc[rf][df], 0, 0, 0);
    }
  }
  // bf16 partials (summed 16-way then bf16-rounded downstream anyway)
  size_t rbase = ((size_t)nc * 16 + h) * 256;
#pragma unroll
  for (int rf = 0; rf < 4; ++rf) {
#pragma unroll
    for (int df = 0; df < 4; ++df)
#pragma unroll
      for (int i = 0; i < 4; ++i) {
        int r = wv * 64 + rf * 16 + lg * 4 + i;
        kvp[(rbase + r) * 64 + df * 16 + lr] = f2bf(acc[rf][df][i]);
      }
    float dv2 = dacc[rf];
    dv2 += __shfl_xor(dv2, 16);
    dv2 += __shfl_xor(dv2, 32);
    if (lg == 0) dpart[rbase + wv * 64 + rf * 16 + lr] = dv2;
  }
}

// ---------------- reduce bf16 partials -> KV^T bf16 [h][d][r] + denv f32
__global__ __launch_bounds__(256) void k_reduce_t(
    const unsigned short* __restrict__ kvp, const float* __restrict__ dpart,
    unsigned short* __restrict__ kvt, float* __restrict__ denv) {
  __shared__ __align__(16) float tile[32][69];
  const int rb = blockIdx.x, h = blockIdx.y;
  const int t = threadIdx.x;
  const int rl = t >> 3, sd = (t & 7) * 8;
  float s[8] = {};
  for (int c = 0; c < 16; ++c) {
    const unsigned short* p =
        kvp + ((size_t)(c * 16 + h) * 256 + rb * 32 + rl) * 64 + sd;
    short8v b8 = *(const short8v*)p;
#pragma unroll
    for (int j = 0; j < 8; ++j) s[j] += bf2f((unsigned short)b8[j]);
  }
#pragma unroll
  for (int j = 0; j < 8; ++j) tile[rl][sd + j] = s[j];
  __syncthreads();
  int d = t >> 2, rj = (t & 3) * 8;
  short8v u;
#pragma unroll
  for (int j = 0; j < 8; ++j) u[j] = (short)f2bf(tile[rj + j][d]);
  *(short8v*)&kvt[((size_t)h * 64 + d) * 256 + rb * 32 + rj] = u;
  if (rb == 0) {
    float sum = 0.f;
    for (int c = 0; c < 16; ++c)
      sum += dpart[(size_t)(c * 16 + h) * 256 + t];
    denv[h * 256 + t] = sum;
  }
}

// ---------------- pass B: fused phi_q (split MFMA) + PV MFMA + normalize
__global__ __launch_bounds__(256) void k_pass_b_mfma(
    const float* __restrict__ ws, const unsigned short* __restrict__ wrmh,
    const unsigned short* __restrict__ wrml,
    const unsigned short* __restrict__ kvt, const float* __restrict__ denv,
    unsigned short* __restrict__ attnb) {
  __shared__ __align__(16) unsigned short kvL[64][264];
  __shared__ __align__(16) unsigned short phL[32][264];
  __shared__ __align__(16) unsigned short qhi[32][72];
  __shared__ __align__(16) unsigned short qlo[32][72];
  __shared__ __align__(16) unsigned short outL[32][80];
  __shared__ __align__(16) float denvL[256];
  __shared__ __align__(16) float nsL[32];
  __shared__ float denp[4][32];
  __shared__ float invL[32];
  const int t = threadIdx.x;
  const int lane = t & 63, wv = t >> 6;
  const int lr = lane & 15, lg = lane >> 4;
  const int nc = blockIdx.x, h = blockIdx.y;   // nc 0..31, 128 rows each
  const float* qb = ws + Q_OFF + (size_t)h * 262144;
  {
    const unsigned short* src = kvt + (size_t)h * 16384 + (size_t)t * 64;
    int d = t >> 2, r0 = (t & 3) * 64;
#pragma unroll
    for (int j = 0; j < 8; ++j)
      *(short8v*)&kvL[d][r0 + j * 8] = *(const short8v*)(src + j * 8);
    denvL[t] = denv[h * 256 + t];
  }
  for (int tile = 0; tile < 4; ++tile) {
    const int n0 = nc * 128 + tile * 32;
    __syncthreads();
    {  // stage q hi/lo + ns
      int sn = t >> 3, sd = (t & 7) * 8;
      const float* qp = qb + (size_t)(n0 + sn) * 64 + sd;
      float4 a0 = *(const float4*)qp;
      float4 a1 = *(const float4*)(qp + 4);
      float vv[8] = {a0.x, a0.y, a0.z, a0.w, a1.x, a1.y, a1.z, a1.w};
      short8v hv, lv;
      float ss = 0.f;
#pragma unroll
      for (int j = 0; j < 8; ++j) {
        ss += vv[j] * vv[j];
        unsigned short hu = f2bf(vv[j]);
        hv[j] = (short)hu;
        lv[j] = (short)f2bf(vv[j] - bf2f(hu));
      }
      *(short8v*)&qhi[sn][sd] = hv;
      *(short8v*)&qlo[sn][sd] = lv;
      ss += __shfl_xor(ss, 1); ss += __shfl_xor(ss, 2); ss += __shfl_xor(ss, 4);
      if ((t & 7) == 0) nsL[sn] = 0.5f * ss;
    }
    __syncthreads();
    float4v p[4][2];
#pragma unroll
    for (int a = 0; a < 4; ++a)
#pragma unroll
      for (int b = 0; b < 2; ++b) p[a][b] = (float4v){0.f, 0.f, 0.f, 0.f};
#pragma unroll
    for (int ks = 0; ks < 2; ++ks) {
      short8v bh[2], bl[2];
#pragma unroll
      for (int nf = 0; nf < 2; ++nf) {
        bh[nf] = *(const short8v*)&qhi[nf * 16 + lr][ks * 32 + lg * 8];
        bl[nf] = *(const short8v*)&qlo[nf * 16 + lr][ks * 32 + lg * 8];
      }
#pragma unroll
      for (int rf = 0; rf < 4; ++rf) {
        size_t wo = (size_t)(wv * 64 + rf * 16 + lr) * 64 + ks * 32 + lg * 8;
        short8v ah = *(const short8v*)&wrmh[wo];
        short8v al = *(const short8v*)&wrml[wo];
#pragma unroll
        for (int nf = 0; nf < 2; ++nf) {
          p[rf][nf] = __builtin_amdgcn_mfma_f32_16x16x32_bf16(ah, bh[nf], p[rf][nf], 0, 0, 0);
          p[rf][nf] = __builtin_amdgcn_mfma_f32_16x16x32_bf16(al, bh[nf], p[rf][nf], 0, 0, 0);
          p[rf][nf] = __builtin_amdgcn_mfma_f32_16x16x32_bf16(ah, bl[nf], p[rf][nf], 0, 0, 0);
        }
      }
    }
    float dnp[2] = {0.f, 0.f};
#pragma unroll
    for (int nf = 0; nf < 2; ++nf) {
      float ns = nsL[nf * 16 + lr];
#pragma unroll
      for (int rf = 0; rf < 4; ++rf) {
        float4 dv4 = *(const float4*)&denvL[wv * 64 + rf * 16 + lg * 4];
        float da[4] = {dv4.x, dv4.y, dv4.z, dv4.w};
        ushort4 u;
        unsigned short uu;
        float s = 0.f;
        uu = f2bf(__expf(p[rf][nf][0] - ns) * 0.0625f); u.x = uu; s += bf2f(uu) * da[0];
        uu = f2bf(__expf(p[rf][nf][1] - ns) * 0.0625f); u.y = uu; s += bf2f(uu) * da[1];
        uu = f2bf(__expf(p[rf][nf][2] - ns) * 0.0625f); u.z = uu; s += bf2f(uu) * da[2];
        uu = f2bf(__expf(p[rf][nf][3] - ns) * 0.0625f); u.w = uu; s += bf2f(uu) * da[3];
        dnp[nf] += s;
        *(ushort4*)&phL[nf * 16 + lr][wv * 64 + rf * 16 + lg * 4] = u;
      }
    }
#pragma unroll
    for (int nf = 0; nf < 2; ++nf) {
      float v2 = dnp[nf];
      v2 += __shfl_xor(v2, 16);
      v2 += __shfl_xor(v2, 32);
      if (lg == 0) denp[wv][nf * 16 + lr] = v2;
    }
    __syncthreads();
    if (t < 32) {
      float dn = denp[0][t] + denp[1][t] + denp[2][t] + denp[3][t];
      invL[t] = 1.0f / (dn + 1e-6f);
    }
    __syncthreads();
    const int nfj = wv & 1;
    float4v o[2];
    o[0] = (float4v){0.f, 0.f, 0.f, 0.f};
    o[1] = (float4v){0.f, 0.f, 0.f, 0.f};
#pragma unroll
    for (int ks = 0; ks < 8; ++ks) {
      short8v af = *(const short8v*)&phL[nfj * 16 + lr][ks * 32 + lg * 8];
#pragma unroll
      for (int j = 0; j < 2; ++j) {
        int df = (wv >> 1) * 2 + j;
        short8v bfr = *(const short8v*)&kvL[df * 16 + lr][ks * 32 + lg * 8];
        o[j] = __builtin_amdgcn_mfma_f32_16x16x32_bf16(af, bfr, o[j], 0, 0, 0);
      }
    }
#pragma unroll
    for (int j = 0; j < 2; ++j) {
      int df = (wv >> 1) * 2 + j;
#pragma unroll
      for (int i = 0; i < 4; ++i) {
        int n = nfj * 16 + lg * 4 + i;
        outL[n][df * 16 + lr] = f2bf(o[j][i] * invL[n]);
      }
    }
    __syncthreads();
    {
      int sn = t >> 3, sd = (t & 7) * 8;
      short8v v8 = *(const short8v*)&outL[sn][sd];
      *(short8v*)&attnb[((size_t)(n0 + sn)) * 1024 + h * 64 + sd] = v8;
    }
  }
}

// ---------------- out GEMM with XCD-aware remap (memory-bound: A-panel reuse)
__global__ __launch_bounds__(256, 2) void k_out_mfma(
    const unsigned short* __restrict__ ab, const unsigned short* __restrict__ wp,
    const float* __restrict__ bp, float* __restrict__ out) {
  __shared__ unsigned short ldsA[8192];
  __shared__ unsigned short ldsB[8192];
  const int t = threadIdx.x;
  const int lane = t & 63, wv = t >> 6;
  const int wm = wv >> 1, wn = wv & 1;
  const int lr = lane & 15, lg = lane >> 4;
  // remap: same-m blocks -> flat ≡ m (mod 8) -> same XCD L2 (A fetched once)
  const int flat = blockIdx.y * 8 + blockIdx.x;       // grid (8,128)
  const int mBase = (flat & 127) * 128;
  const int jBase = (flat >> 7) * 128;
  float4v acc[4][4];
#pragma unroll
  for (int a = 0; a < 4; ++a)
#pragma unroll
    for (int b = 0; b < 4; ++b) acc[a][b] = (float4v){0.f, 0.f, 0.f, 0.f};

  for (int kt = 0; kt < 1024; kt += 64) {
    __syncthreads();
    stage_tile(ab + (size_t)mBase * 1024 + kt, ldsA, t);
    stage_tile(wp + (size_t)jBase * 1024 + kt, ldsB, t);
    asm volatile("s_waitcnt vmcnt(0)");
    __syncthreads();
#pragma unroll
    for (int ks = 0; ks < 2; ++ks) {
      const int seg = ks * 4 + lg;
      short8v a[4], b[4];
#pragma unroll
      for (int f = 0; f < 4; ++f) {
        a[f] = read_frag(ldsA, wm * 64 + f * 16 + lr, seg);
        b[f] = read_frag(ldsB, wn * 64 + f * 16 + lr, seg);
      }
#pragma unroll
      for (int fm = 0; fm < 4; ++fm)
#pragma unroll
        for (int fn = 0; fn < 4; ++fn)
          acc[fm][fn] = __builtin_amdgcn_mfma_f32_16x16x32_bf16(
              a[fm], b[fn], acc[fm][fn], 0, 0, 0);
    }
  }
#pragma unroll
  for (int fn = 0; fn < 4; ++fn) {
    int j = jBase + wn * 64 + fn * 16 + lr;
    float bias = bp[j];
#pragma unroll
    for (int fm = 0; fm < 4; ++fm) {
      int m0 = mBase + wm * 64 + fm * 16 + lg * 4;
#pragma unroll
      for (int r = 0; r < 4; ++r)
        out[(size_t)(m0 + r) * 1024 + j] = acc[fm][fn][r] + bias;
    }
  }
}

}  // namespace

extern "C" void kernel_launch(void* const* d_in, const int* in_sizes, int n_in,
                              void* d_out, int out_size, void* d_ws,
                              size_t ws_size, hipStream_t stream) {
  const float *x = nullptr, *Wqkv = nullptr, *bqkv = nullptr;
  const float *Wproj = nullptr, *bproj = nullptr, *Wrm = nullptr;
  for (int i = 0; i < n_in; ++i) {
    switch (in_sizes[i]) {
      case 16777216: x     = (const float*)d_in[i]; break;
      case 3145728:  Wqkv  = (const float*)d_in[i]; break;
      case 3072:     bqkv  = (const float*)d_in[i]; break;
      case 1048576:  Wproj = (const float*)d_in[i]; break;
      case 1024:     bproj = (const float*)d_in[i]; break;
      case 16384:    Wrm   = (const float*)d_in[i]; break;
      default: break;
    }
  }
  float* out = (float*)d_out;
  float* ws = (float*)d_ws;

  if (!x || !Wqkv || !bqkv || !Wproj || !bproj || !Wrm) {
    k_sent<<<1, 1, 0, stream>>>(out, 2000.0f);
    return;
  }
  if (ws_size < WS_ELEMS * sizeof(float)) {
    k_sent<<<1, 1, 0, stream>>>(out, 1000.0f);
    return;
  }

  unsigned short* xh   = (unsigned short*)(ws + XH_OFF);
  unsigned short* wh   = (unsigned short*)(ws + WH_OFF);
  unsigned short* wl   = (unsigned short*)(ws + WL_OFF);
  unsigned short* wrmh = (unsigned short*)(ws + WRMH_OFF);
  unsigned short* wrml = (unsigned short*)(ws + WRML_OFF);
  unsigned short* ambf = (unsigned short*)(ws + ATTNB_OFF);
  unsigned short* wph  = (unsigned short*)(ws + WPH_OFF);
  unsigned short* kvt  = (unsigned short*)(ws + KVT_OFF);
  unsigned short* vb   = (unsigned short*)(ws + VB_OFF);
  unsigned short* kvp  = (unsigned short*)(ws + KVP_OFF);

  k_conv_split<<<3072, 256, 0, stream>>>(Wqkv, wh, wl, 786432);
  k_conv_split<<<16, 256, 0, stream>>>(Wrm, wrmh, wrml, 4096);
  k_conv_hi<<<1024, 256, 0, stream>>>(Wproj, wph, 262144);

  for (int b = 0; b < 4; ++b) {
    const float* x_b = x + (size_t)b * 4096 * 1024;
    unsigned short* attnb_b = ambf + (size_t)b * 4194304;
    k_conv_hi<<<4096, 256, 0, stream>>>(x_b, xh, 1048576);
    // q/k columns: 2-MFMA (x hi only, w split); v columns: plain bf16 -> vb
    k_qkv_mfma<<<dim3(16, 32), 256, 0, stream>>>(xh, wh, wl, bqkv, ws);
    k_qkv_v<<<dim3(8, 32), 256, 0, stream>>>(xh, wh, bqkv, vb);
    k_pass_a_mfma<<<dim3(16, 16), 256, 0, stream>>>(ws, vb, wrmh, wrml,
                                                    kvp, ws + DPART_OFF);
    k_reduce_t<<<dim3(8, 16), 256, 0, stream>>>(kvp, ws + DPART_OFF,
                                                kvt, ws + DENV_OFF);
    k_pass_b_mfma<<<dim3(32, 16), 256, 0, stream>>>(ws, wrmh, wrml, kvt,
                                                    ws + DENV_OFF, attnb_b);
  }
  k_out_mfma<<<dim3(8, 128), 256, 0, stream>>>(ambf, wph, bproj, out);
}

// Round 10
// 368.359 us; speedup vs baseline: 6.6857x; 1.2896x over previous
//
#include <hip/hip_runtime.h>
#include <hip/hip_bf16.h>

namespace {

typedef __attribute__((ext_vector_type(8))) short short8v;   // 8 bf16
typedef __attribute__((ext_vector_type(4))) float float4v;   // 4 f32

// ---- workspace layout (float-slot offsets), ALL-BATCH fused ----
// B=4, H=16, N=4096, D=64, r=256. 219.3 MB total (ws >= 222.6 MB proven r1).
constexpr size_t QB1      = 4194304;                 // 16h*4096*64 per batch
constexpr size_t Q_OFF    = 0;                       // f32 [4][16h][4096][64]
constexpr size_t K_OFF    = 16777216;                // f32 [4][16h][4096][64]
constexpr size_t ATTNB_OFF = K_OFF;                  // ushort overlay (K dead)
constexpr size_t V_OFF    = 33554432;                // ushort [4][16h][4096][64]
constexpr size_t XH_OFF   = 41943040;                // ushort [16384][1024]
constexpr size_t KVP_OFF  = XH_OFF;                  // ushort overlay (xh dead)
constexpr size_t DPART_OFF = 50331648;               // f32 [4][16nc][16h][256]
constexpr size_t KVT_OFF  = DPART_OFF + 262144;      // ushort [4][16h][64][256]
constexpr size_t DENV_OFF = KVT_OFF + 524288;        // f32 [4][16h][256]
constexpr size_t WH_OFF   = DENV_OFF + 16384;        // ushort Wqkv hi
constexpr size_t WL_OFF   = WH_OFF + 1572864;        // ushort Wqkv lo
constexpr size_t WRMH_OFF = WL_OFF + 1572864;        // ushort Wrm hi
constexpr size_t WRML_OFF = WRMH_OFF + 8192;
constexpr size_t WPH_OFF  = WRML_OFF + 8192;         // ushort Wproj hi
constexpr size_t WS_ELEMS = WPH_OFF + 524288;        // 54,820,864 (~219.3 MB)

__device__ __forceinline__ unsigned short f2bf(float f) {
  unsigned int u = __float_as_uint(f);
  u += 0x7FFFu + ((u >> 16) & 1u);                   // round-to-nearest-even
  return (unsigned short)(u >> 16);
}
__device__ __forceinline__ float bf2f(unsigned short u) {
  return __uint_as_float((unsigned)u << 16);
}

__global__ void k_sent(float* out, float v) { out[0] = v; }

// ---------------- fp32 -> bf16 hi+lo split (weights)
__global__ __launch_bounds__(256) void k_conv_split(
    const float* __restrict__ src, unsigned short* __restrict__ hi,
    unsigned short* __restrict__ lo, int n4) {
  int i = blockIdx.x * 256 + threadIdx.x;
  if (i >= n4) return;
  float4 v = *(const float4*)&src[(size_t)i * 4];
  ushort4 h, l;
  h.x = f2bf(v.x); l.x = f2bf(v.x - bf2f(h.x));
  h.y = f2bf(v.y); l.y = f2bf(v.y - bf2f(h.y));
  h.z = f2bf(v.z); l.z = f2bf(v.z - bf2f(h.z));
  h.w = f2bf(v.w); l.w = f2bf(v.w - bf2f(h.w));
  *(ushort4*)&hi[(size_t)i * 4] = h;
  *(ushort4*)&lo[(size_t)i * 4] = l;
}

__global__ __launch_bounds__(256) void k_conv_hi(
    const float* __restrict__ src, unsigned short* __restrict__ hi, int n4) {
  int i = blockIdx.x * 256 + threadIdx.x;
  if (i >= n4) return;
  float4 v = *(const float4*)&src[(size_t)i * 4];
  ushort4 h = {f2bf(v.x), f2bf(v.y), f2bf(v.z), f2bf(v.w)};
  *(ushort4*)&hi[(size_t)i * 4] = h;
}

// ---- stage [128 rows][64 k] bf16 tile via global_load_lds (verified) ----
__device__ __forceinline__ void stage_tile(const unsigned short* __restrict__ src,
                                           unsigned short* __restrict__ dst,
                                           int t) {
#pragma unroll
  for (int i = 0; i < 4; ++i) {
    int c = i * 256 + t;
    int row = c >> 3;
    int seg = (c & 7) ^ (row & 7);
    __builtin_amdgcn_global_load_lds(
        (const __attribute__((address_space(1))) void*)(src + (size_t)row * 1024 + seg * 8),
        (__attribute__((address_space(3))) void*)(dst + (size_t)c * 8),
        16, 0, 0);
  }
}

__device__ __forceinline__ short8v read_frag(const unsigned short* lds, int row,
                                             int seg) {
  return *(const short8v*)&lds[(size_t)row * 64 + ((seg ^ (row & 7)) * 8)];
}

// ---------------- qkv GEMM q/k (j<2048): 2-MFMA, all batches (M=16384)
__global__ __launch_bounds__(256, 2) void k_qkv_mfma(
    const unsigned short* __restrict__ xh,
    const unsigned short* __restrict__ wh, const unsigned short* __restrict__ wl,
    const float* __restrict__ bq, float* __restrict__ ws) {
  __shared__ unsigned short ldsA[8192];
  __shared__ unsigned short ldsB[2][8192];
  const int t = threadIdx.x;
  const int lane = t & 63, wv = t >> 6;
  const int wm = wv >> 1, wn = wv & 1;
  const int lr = lane & 15, lg = lane >> 4;
  const int mBase = blockIdx.y * 128;           // global row 0..16383
  const int jBase = blockIdx.x * 128;           // < 2048 (q/k)
  const int gb = mBase >> 12;                   // batch
  const int nn0 = mBase & 4095;                 // n within batch
  float4v acc[4][4];
#pragma unroll
  for (int a = 0; a < 4; ++a)
#pragma unroll
    for (int b = 0; b < 4; ++b) acc[a][b] = (float4v){0.f, 0.f, 0.f, 0.f};

  for (int kt = 0; kt < 1024; kt += 64) {
    __syncthreads();
    stage_tile(xh + (size_t)mBase * 1024 + kt, ldsA, t);
    stage_tile(wh + (size_t)jBase * 1024 + kt, ldsB[0], t);
    stage_tile(wl + (size_t)jBase * 1024 + kt, ldsB[1], t);
    asm volatile("s_waitcnt vmcnt(0)");
    __syncthreads();
#pragma unroll
    for (int ks = 0; ks < 2; ++ks) {
      const int seg = ks * 4 + lg;
      short8v ah[4], bh[4], bl[4];
#pragma unroll
      for (int f = 0; f < 4; ++f) {
        ah[f] = read_frag(ldsA, wm * 64 + f * 16 + lr, seg);
        int rb = wn * 64 + f * 16 + lr;
        bh[f] = read_frag(ldsB[0], rb, seg);
        bl[f] = read_frag(ldsB[1], rb, seg);
      }
#pragma unroll
      for (int fm = 0; fm < 4; ++fm)
#pragma unroll
        for (int fn = 0; fn < 4; ++fn) {
          acc[fm][fn] = __builtin_amdgcn_mfma_f32_16x16x32_bf16(
              ah[fm], bh[fn], acc[fm][fn], 0, 0, 0);
          acc[fm][fn] = __builtin_amdgcn_mfma_f32_16x16x32_bf16(
              ah[fm], bl[fn], acc[fm][fn], 0, 0, 0);
        }
    }
  }
#pragma unroll
  for (int fn = 0; fn < 4; ++fn) {
    int j = jBase + wn * 64 + fn * 16 + lr;
    int t3 = j >> 10, h = (j >> 6) & 15, dd = j & 63;
    float bias = bq[j];
    float* op = ws + (t3 ? K_OFF : Q_OFF) + (size_t)gb * QB1 +
                (size_t)h * 262144 + dd;
#pragma unroll
    for (int fm = 0; fm < 4; ++fm) {
      int n0 = nn0 + wm * 64 + fm * 16 + lg * 4;
#pragma unroll
      for (int r = 0; r < 4; ++r)
        op[(size_t)(n0 + r) * 64] = acc[fm][fn][r] + bias;
    }
  }
}

// ---------------- qkv GEMM v (j in [2048,3072)): plain bf16, all batches
__global__ __launch_bounds__(256, 2) void k_qkv_v(
    const unsigned short* __restrict__ xh, const unsigned short* __restrict__ wh,
    const float* __restrict__ bq, unsigned short* __restrict__ vb) {
  __shared__ unsigned short ldsA[8192];
  __shared__ unsigned short ldsB[8192];
  const int t = threadIdx.x;
  const int lane = t & 63, wv = t >> 6;
  const int wm = wv >> 1, wn = wv & 1;
  const int lr = lane & 15, lg = lane >> 4;
  const int mBase = blockIdx.y * 128;
  const int jBase = 2048 + blockIdx.x * 128;
  const int gb = mBase >> 12;
  const int nn0 = mBase & 4095;
  float4v acc[4][4];
#pragma unroll
  for (int a = 0; a < 4; ++a)
#pragma unroll
    for (int b = 0; b < 4; ++b) acc[a][b] = (float4v){0.f, 0.f, 0.f, 0.f};

  for (int kt = 0; kt < 1024; kt += 64) {
    __syncthreads();
    stage_tile(xh + (size_t)mBase * 1024 + kt, ldsA, t);
    stage_tile(wh + (size_t)jBase * 1024 + kt, ldsB, t);
    asm volatile("s_waitcnt vmcnt(0)");
    __syncthreads();
#pragma unroll
    for (int ks = 0; ks < 2; ++ks) {
      const int seg = ks * 4 + lg;
      short8v a[4], b[4];
#pragma unroll
      for (int f = 0; f < 4; ++f) {
        a[f] = read_frag(ldsA, wm * 64 + f * 16 + lr, seg);
        b[f] = read_frag(ldsB, wn * 64 + f * 16 + lr, seg);
      }
#pragma unroll
      for (int fm = 0; fm < 4; ++fm)
#pragma unroll
        for (int fn = 0; fn < 4; ++fn)
          acc[fm][fn] = __builtin_amdgcn_mfma_f32_16x16x32_bf16(
              a[fm], b[fn], acc[fm][fn], 0, 0, 0);
    }
  }
#pragma unroll
  for (int fn = 0; fn < 4; ++fn) {
    int j = jBase + wn * 64 + fn * 16 + lr;
    int h = (j >> 6) & 15, dd = j & 63;
    float bias = bq[j];
    unsigned short* op = vb + (size_t)gb * 4194304 + (size_t)h * 262144 + dd;
#pragma unroll
    for (int fm = 0; fm < 4; ++fm) {
      int n0 = nn0 + wm * 64 + fm * 16 + lg * 4;
#pragma unroll
      for (int r = 0; r < 4; ++r)
        op[(size_t)(n0 + r) * 64] = f2bf(acc[fm][fn][r] + bias);
    }
  }
}

// ---------------- pass A: fused phi_k (split MFMA) + KV MFMA, batched z
__global__ __launch_bounds__(256) void k_pass_a_mfma(
    const float* __restrict__ ws, const unsigned short* __restrict__ vbb,
    const unsigned short* __restrict__ wrmh,
    const unsigned short* __restrict__ wrml, unsigned short* __restrict__ kvp,
    float* __restrict__ dpart) {
  __shared__ __align__(16) unsigned short khi[32][72];
  __shared__ __align__(16) unsigned short klo[32][72];
  __shared__ __align__(16) unsigned short vT[64][40];
  __shared__ __align__(16) unsigned short phL[256][40];
  __shared__ __align__(16) float nsL[32];
  const int t = threadIdx.x;
  const int lane = t & 63, wv = t >> 6;
  const int lr = lane & 15, lg = lane >> 4;
  const int nc = blockIdx.x, h = blockIdx.y, gb = blockIdx.z;
  const float* kb = ws + K_OFF + (size_t)gb * QB1 + (size_t)h * 262144;
  const unsigned short* vbh = vbb + (size_t)gb * 4194304 + (size_t)h * 262144;
  float4v acc[4][4];
#pragma unroll
  for (int a = 0; a < 4; ++a)
#pragma unroll
    for (int b = 0; b < 4; ++b) acc[a][b] = (float4v){0.f, 0.f, 0.f, 0.f};
  float dacc[4] = {};

  for (int tile = 0; tile < 8; ++tile) {
    const int n0 = nc * 256 + tile * 32;
    __syncthreads();
    {  // stage k hi/lo + ns
      int sn = t >> 3, sd = (t & 7) * 8;
      const float* kp = kb + (size_t)(n0 + sn) * 64 + sd;
      float4 a0 = *(const float4*)kp;
      float4 a1 = *(const float4*)(kp + 4);
      float vv[8] = {a0.x, a0.y, a0.z, a0.w, a1.x, a1.y, a1.z, a1.w};
      short8v hv, lv;
      float ss = 0.f;
#pragma unroll
      for (int j = 0; j < 8; ++j) {
        ss += vv[j] * vv[j];
        unsigned short hu = f2bf(vv[j]);
        hv[j] = (short)hu;
        lv[j] = (short)f2bf(vv[j] - bf2f(hu));
      }
      *(short8v*)&khi[sn][sd] = hv;
      *(short8v*)&klo[sn][sd] = lv;
      ss += __shfl_xor(ss, 1); ss += __shfl_xor(ss, 2); ss += __shfl_xor(ss, 4);
      if ((t & 7) == 0) nsL[sn] = 0.5f * ss;
    }
    {  // stage v (bf16) transposed
      int sn = t & 31, sd = (t >> 5) * 8;
      short8v v8 = *(const short8v*)&vbh[(size_t)(n0 + sn) * 64 + sd];
#pragma unroll
      for (int j = 0; j < 8; ++j) vT[sd + j][sn] = (unsigned short)v8[j];
    }
    __syncthreads();
    float4v p[2][4];
#pragma unroll
    for (int a = 0; a < 2; ++a)
#pragma unroll
      for (int b = 0; b < 4; ++b) p[a][b] = (float4v){0.f, 0.f, 0.f, 0.f};
#pragma unroll
    for (int ks = 0; ks < 2; ++ks) {
      short8v ah[2], al[2];
#pragma unroll
      for (int nf = 0; nf < 2; ++nf) {
        ah[nf] = *(const short8v*)&khi[nf * 16 + lr][ks * 32 + lg * 8];
        al[nf] = *(const short8v*)&klo[nf * 16 + lr][ks * 32 + lg * 8];
      }
#pragma unroll
      for (int rf = 0; rf < 4; ++rf) {
        size_t wo = (size_t)(wv * 64 + rf * 16 + lr) * 64 + ks * 32 + lg * 8;
        short8v bh = *(const short8v*)&wrmh[wo];
        short8v bl = *(const short8v*)&wrml[wo];
#pragma unroll
        for (int nf = 0; nf < 2; ++nf) {
          p[nf][rf] = __builtin_amdgcn_mfma_f32_16x16x32_bf16(ah[nf], bh, p[nf][rf], 0, 0, 0);
          p[nf][rf] = __builtin_amdgcn_mfma_f32_16x16x32_bf16(ah[nf], bl, p[nf][rf], 0, 0, 0);
          p[nf][rf] = __builtin_amdgcn_mfma_f32_16x16x32_bf16(al[nf], bh, p[nf][rf], 0, 0, 0);
        }
      }
    }
#pragma unroll
    for (int nf = 0; nf < 2; ++nf) {
      float4 ns4 = *(const float4*)&nsL[nf * 16 + lg * 4];
      float nsa[4] = {ns4.x, ns4.y, ns4.z, ns4.w};
#pragma unroll
      for (int rf = 0; rf < 4; ++rf) {
        ushort4 u;
        float s = 0.f;
        unsigned short uu;
        uu = f2bf(__expf(p[nf][rf][0] - nsa[0]) * 0.0625f); u.x = uu; s += bf2f(uu);
        uu = f2bf(__expf(p[nf][rf][1] - nsa[1]) * 0.0625f); u.y = uu; s += bf2f(uu);
        uu = f2bf(__expf(p[nf][rf][2] - nsa[2]) * 0.0625f); u.z = uu; s += bf2f(uu);
        uu = f2bf(__expf(p[nf][rf][3] - nsa[3]) * 0.0625f); u.w = uu; s += bf2f(uu);
        dacc[rf] += s;
        *(ushort4*)&phL[wv * 64 + rf * 16 + lr][nf * 16 + lg * 4] = u;
      }
    }
    {
      short8v af[4], bf_[4];
#pragma unroll
      for (int rf = 0; rf < 4; ++rf)
        af[rf] = *(const short8v*)&phL[wv * 64 + rf * 16 + lr][lg * 8];
#pragma unroll
      for (int df = 0; df < 4; ++df)
        bf_[df] = *(const short8v*)&vT[df * 16 + lr][lg * 8];
#pragma unroll
      for (int rf = 0; rf < 4; ++rf)
#pragma unroll
        for (int df = 0; df < 4; ++df)
          acc[rf][df] = __builtin_amdgcn_mfma_f32_16x16x32_bf16(
              af[rf], bf_[df], acc[rf][df], 0, 0, 0);
    }
  }
  size_t rbase = (((size_t)gb * 16 + nc) * 16 + h) * 256;
#pragma unroll
  for (int rf = 0; rf < 4; ++rf) {
#pragma unroll
    for (int df = 0; df < 4; ++df)
#pragma unroll
      for (int i = 0; i < 4; ++i) {
        int r = wv * 64 + rf * 16 + lg * 4 + i;
        kvp[(rbase + r) * 64 + df * 16 + lr] = f2bf(acc[rf][df][i]);
      }
    float dv2 = dacc[rf];
    dv2 += __shfl_xor(dv2, 16);
    dv2 += __shfl_xor(dv2, 32);
    if (lg == 0) dpart[rbase + wv * 64 + rf * 16 + lr] = dv2;
  }
}

// ---------------- reduce bf16 partials -> KV^T bf16 + denv, batched z
__global__ __launch_bounds__(256) void k_reduce_t(
    const unsigned short* __restrict__ kvp, const float* __restrict__ dpart,
    unsigned short* __restrict__ kvt, float* __restrict__ denv) {
  __shared__ __align__(16) float tile[32][69];
  const int rb = blockIdx.x, h = blockIdx.y, gb = blockIdx.z;
  const int t = threadIdx.x;
  const int rl = t >> 3, sd = (t & 7) * 8;
  float s[8] = {};
  for (int c = 0; c < 16; ++c) {
    const unsigned short* p = kvp +
        ((((size_t)gb * 16 + c) * 16 + h) * 256 + rb * 32 + rl) * 64 + sd;
    short8v b8 = *(const short8v*)p;
#pragma unroll
    for (int j = 0; j < 8; ++j) s[j] += bf2f((unsigned short)b8[j]);
  }
#pragma unroll
  for (int j = 0; j < 8; ++j) tile[rl][sd + j] = s[j];
  __syncthreads();
  int d = t >> 2, rj = (t & 3) * 8;
  short8v u;
#pragma unroll
  for (int j = 0; j < 8; ++j) u[j] = (short)f2bf(tile[rj + j][d]);
  *(short8v*)&kvt[(((size_t)gb * 16 + h) * 64 + d) * 256 + rb * 32 + rj] = u;
  if (rb == 0) {
    float sum = 0.f;
    for (int c = 0; c < 16; ++c)
      sum += dpart[(((size_t)gb * 16 + c) * 16 + h) * 256 + t];
    denv[((size_t)gb * 16 + h) * 256 + t] = sum;
  }
}

// ---------------- pass B: fused phi_q (split MFMA) + PV MFMA, batched z
__global__ __launch_bounds__(256) void k_pass_b_mfma(
    const float* __restrict__ ws, const unsigned short* __restrict__ wrmh,
    const unsigned short* __restrict__ wrml,
    const unsigned short* __restrict__ kvt, const float* __restrict__ denv,
    unsigned short* __restrict__ attnb) {
  __shared__ __align__(16) unsigned short kvL[64][264];
  __shared__ __align__(16) unsigned short phL[32][264];
  __shared__ __align__(16) unsigned short qhi[32][72];
  __shared__ __align__(16) unsigned short qlo[32][72];
  __shared__ __align__(16) unsigned short outL[32][80];
  __shared__ __align__(16) float denvL[256];
  __shared__ __align__(16) float nsL[32];
  __shared__ float denp[4][32];
  __shared__ float invL[32];
  const int t = threadIdx.x;
  const int lane = t & 63, wv = t >> 6;
  const int lr = lane & 15, lg = lane >> 4;
  const int nc = blockIdx.x, h = blockIdx.y, gb = blockIdx.z;
  const float* qb = ws + Q_OFF + (size_t)gb * QB1 + (size_t)h * 262144;
  unsigned short* ao = attnb + (size_t)gb * 4194304;
  {
    const unsigned short* src =
        kvt + ((size_t)gb * 16 + h) * 16384 + (size_t)t * 64;
    int d = t >> 2, r0 = (t & 3) * 64;
#pragma unroll
    for (int j = 0; j < 8; ++j)
      *(short8v*)&kvL[d][r0 + j * 8] = *(const short8v*)(src + j * 8);
    denvL[t] = denv[((size_t)gb * 16 + h) * 256 + t];
  }
  for (int tile = 0; tile < 4; ++tile) {
    const int n0 = nc * 128 + tile * 32;
    __syncthreads();
    {  // stage q hi/lo + ns
      int sn = t >> 3, sd = (t & 7) * 8;
      const float* qp = qb + (size_t)(n0 + sn) * 64 + sd;
      float4 a0 = *(const float4*)qp;
      float4 a1 = *(const float4*)(qp + 4);
      float vv[8] = {a0.x, a0.y, a0.z, a0.w, a1.x, a1.y, a1.z, a1.w};
      short8v hv, lv;
      float ss = 0.f;
#pragma unroll
      for (int j = 0; j < 8; ++j) {
        ss += vv[j] * vv[j];
        unsigned short hu = f2bf(vv[j]);
        hv[j] = (short)hu;
        lv[j] = (short)f2bf(vv[j] - bf2f(hu));
      }
      *(short8v*)&qhi[sn][sd] = hv;
      *(short8v*)&qlo[sn][sd] = lv;
      ss += __shfl_xor(ss, 1); ss += __shfl_xor(ss, 2); ss += __shfl_xor(ss, 4);
      if ((t & 7) == 0) nsL[sn] = 0.5f * ss;
    }
    __syncthreads();
    float4v p[4][2];
#pragma unroll
    for (int a = 0; a < 4; ++a)
#pragma unroll
      for (int b = 0; b < 2; ++b) p[a][b] = (float4v){0.f, 0.f, 0.f, 0.f};
#pragma unroll
    for (int ks = 0; ks < 2; ++ks) {
      short8v bh[2], bl[2];
#pragma unroll
      for (int nf = 0; nf < 2; ++nf) {
        bh[nf] = *(const short8v*)&qhi[nf * 16 + lr][ks * 32 + lg * 8];
        bl[nf] = *(const short8v*)&qlo[nf * 16 + lr][ks * 32 + lg * 8];
      }
#pragma unroll
      for (int rf = 0; rf < 4; ++rf) {
        size_t wo = (size_t)(wv * 64 + rf * 16 + lr) * 64 + ks * 32 + lg * 8;
        short8v ah = *(const short8v*)&wrmh[wo];
        short8v al = *(const short8v*)&wrml[wo];
#pragma unroll
        for (int nf = 0; nf < 2; ++nf) {
          p[rf][nf] = __builtin_amdgcn_mfma_f32_16x16x32_bf16(ah, bh[nf], p[rf][nf], 0, 0, 0);
          p[rf][nf] = __builtin_amdgcn_mfma_f32_16x16x32_bf16(al, bh[nf], p[rf][nf], 0, 0, 0);
          p[rf][nf] = __builtin_amdgcn_mfma_f32_16x16x32_bf16(ah, bl[nf], p[rf][nf], 0, 0, 0);
        }
      }
    }
    float dnp[2] = {0.f, 0.f};
#pragma unroll
    for (int nf = 0; nf < 2; ++nf) {
      float ns = nsL[nf * 16 + lr];
#pragma unroll
      for (int rf = 0; rf < 4; ++rf) {
        float4 dv4 = *(const float4*)&denvL[wv * 64 + rf * 16 + lg * 4];
        float da[4] = {dv4.x, dv4.y, dv4.z, dv4.w};
        ushort4 u;
        unsigned short uu;
        float s = 0.f;
        uu = f2bf(__expf(p[rf][nf][0] - ns) * 0.0625f); u.x = uu; s += bf2f(uu) * da[0];
        uu = f2bf(__expf(p[rf][nf][1] - ns) * 0.0625f); u.y = uu; s += bf2f(uu) * da[1];
        uu = f2bf(__expf(p[rf][nf][2] - ns) * 0.0625f); u.z = uu; s += bf2f(uu) * da[2];
        uu = f2bf(__expf(p[rf][nf][3] - ns) * 0.0625f); u.w = uu; s += bf2f(uu) * da[3];
        dnp[nf] += s;
        *(ushort4*)&phL[nf * 16 + lr][wv * 64 + rf * 16 + lg * 4] = u;
      }
    }
#pragma unroll
    for (int nf = 0; nf < 2; ++nf) {
      float v2 = dnp[nf];
      v2 += __shfl_xor(v2, 16);
      v2 += __shfl_xor(v2, 32);
      if (lg == 0) denp[wv][nf * 16 + lr] = v2;
    }
    __syncthreads();
    if (t < 32) {
      float dn = denp[0][t] + denp[1][t] + denp[2][t] + denp[3][t];
      invL[t] = 1.0f / (dn + 1e-6f);
    }
    __syncthreads();
    const int nfj = wv & 1;
    float4v o[2];
    o[0] = (float4v){0.f, 0.f, 0.f, 0.f};
    o[1] = (float4v){0.f, 0.f, 0.f, 0.f};
#pragma unroll
    for (int ks = 0; ks < 8; ++ks) {
      short8v af = *(const short8v*)&phL[nfj * 16 + lr][ks * 32 + lg * 8];
#pragma unroll
      for (int j = 0; j < 2; ++j) {
        int df = (wv >> 1) * 2 + j;
        short8v bfr = *(const short8v*)&kvL[df * 16 + lr][ks * 32 + lg * 8];
        o[j] = __builtin_amdgcn_mfma_f32_16x16x32_bf16(af, bfr, o[j], 0, 0, 0);
      }
    }
#pragma unroll
    for (int j = 0; j < 2; ++j) {
      int df = (wv >> 1) * 2 + j;
#pragma unroll
      for (int i = 0; i < 4; ++i) {
        int n = nfj * 16 + lg * 4 + i;
        outL[n][df * 16 + lr] = f2bf(o[j][i] * invL[n]);
      }
    }
    __syncthreads();
    {
      int sn = t >> 3, sd = (t & 7) * 8;
      short8v v8 = *(const short8v*)&outL[sn][sd];
      *(short8v*)&ao[((size_t)(n0 + sn)) * 1024 + h * 64 + sd] = v8;
    }
  }
}

// ---------------- out GEMM: XCD remap + LDS-staged full-line writes
__global__ __launch_bounds__(256, 2) void k_out_mfma(
    const unsigned short* __restrict__ ab, const unsigned short* __restrict__ wp,
    const float* __restrict__ bp, float* __restrict__ out) {
  __shared__ unsigned short ldsA[8192];
  __shared__ unsigned short ldsB[8192];
  __shared__ __align__(16) float foutS[64][132];
  const int t = threadIdx.x;
  const int lane = t & 63, wv = t >> 6;
  const int wm = wv >> 1, wn = wv & 1;
  const int lr = lane & 15, lg = lane >> 4;
  // remap: same-m blocks -> flat ≡ m (mod 8) -> same XCD L2 (verified r9)
  const int flat = blockIdx.y * 8 + blockIdx.x;       // grid (8,128)
  const int mBase = (flat & 127) * 128;
  const int jBase = (flat >> 7) * 128;
  float4v acc[4][4];
#pragma unroll
  for (int a = 0; a < 4; ++a)
#pragma unroll
    for (int b = 0; b < 4; ++b) acc[a][b] = (float4v){0.f, 0.f, 0.f, 0.f};

  for (int kt = 0; kt < 1024; kt += 64) {
    __syncthreads();
    stage_tile(ab + (size_t)mBase * 1024 + kt, ldsA, t);
    stage_tile(wp + (size_t)jBase * 1024 + kt, ldsB, t);
    asm volatile("s_waitcnt vmcnt(0)");
    __syncthreads();
#pragma unroll
    for (int ks = 0; ks < 2; ++ks) {
      const int seg = ks * 4 + lg;
      short8v a[4], b[4];
#pragma unroll
      for (int f = 0; f < 4; ++f) {
        a[f] = read_frag(ldsA, wm * 64 + f * 16 + lr, seg);
        b[f] = read_frag(ldsB, wn * 64 + f * 16 + lr, seg);
      }
#pragma unroll
      for (int fm = 0; fm < 4; ++fm)
#pragma unroll
        for (int fn = 0; fn < 4; ++fn)
          acc[fm][fn] = __builtin_amdgcn_mfma_f32_16x16x32_bf16(
              a[fm], b[fn], acc[fm][fn], 0, 0, 0);
    }
  }
  float biasv[4];
#pragma unroll
  for (int fn = 0; fn < 4; ++fn)
    biasv[fn] = bp[jBase + wn * 64 + fn * 16 + lr];
#pragma unroll
  for (int ph = 0; ph < 2; ++ph) {
    __syncthreads();
    if (wm == ph) {
#pragma unroll
      for (int fm = 0; fm < 4; ++fm)
#pragma unroll
        for (int fn = 0; fn < 4; ++fn)
#pragma unroll
          for (int r = 0; r < 4; ++r)
            foutS[fm * 16 + lg * 4 + r][wn * 64 + fn * 16 + lr] =
                acc[fm][fn][r] + biasv[fn];
    }
    __syncthreads();
#pragma unroll
    for (int i = 0; i < 8; ++i) {     // 512B-contiguous row segments
      int row = i * 8 + (t >> 5);
      int c0 = (t & 31) * 4;
      *(float4*)&out[(size_t)(mBase + ph * 64 + row) * 1024 + jBase + c0] =
          *(const float4*)&foutS[row][c0];
    }
  }
}

}  // namespace

extern "C" void kernel_launch(void* const* d_in, const int* in_sizes, int n_in,
                              void* d_out, int out_size, void* d_ws,
                              size_t ws_size, hipStream_t stream) {
  const float *x = nullptr, *Wqkv = nullptr, *bqkv = nullptr;
  const float *Wproj = nullptr, *bproj = nullptr, *Wrm = nullptr;
  for (int i = 0; i < n_in; ++i) {
    switch (in_sizes[i]) {
      case 16777216: x     = (const float*)d_in[i]; break;
      case 3145728:  Wqkv  = (const float*)d_in[i]; break;
      case 3072:     bqkv  = (const float*)d_in[i]; break;
      case 1048576:  Wproj = (const float*)d_in[i]; break;
      case 1024:     bproj = (const float*)d_in[i]; break;
      case 16384:    Wrm   = (const float*)d_in[i]; break;
      default: break;
    }
  }
  float* out = (float*)d_out;
  float* ws = (float*)d_ws;

  if (!x || !Wqkv || !bqkv || !Wproj || !bproj || !Wrm) {
    k_sent<<<1, 1, 0, stream>>>(out, 2000.0f);
    return;
  }
  if (ws_size < WS_ELEMS * sizeof(float)) {
    k_sent<<<1, 1, 0, stream>>>(out, 1000.0f);
    return;
  }

  unsigned short* xh   = (unsigned short*)(ws + XH_OFF);
  unsigned short* wh   = (unsigned short*)(ws + WH_OFF);
  unsigned short* wl   = (unsigned short*)(ws + WL_OFF);
  unsigned short* wrmh = (unsigned short*)(ws + WRMH_OFF);
  unsigned short* wrml = (unsigned short*)(ws + WRML_OFF);
  unsigned short* ambf = (unsigned short*)(ws + ATTNB_OFF);
  unsigned short* wph  = (unsigned short*)(ws + WPH_OFF);
  unsigned short* kvt  = (unsigned short*)(ws + KVT_OFF);
  unsigned short* vb   = (unsigned short*)(ws + V_OFF);
  unsigned short* kvp  = (unsigned short*)(ws + KVP_OFF);

  // weight + input conversions (once, all batches)
  k_conv_split<<<3072, 256, 0, stream>>>(Wqkv, wh, wl, 786432);
  k_conv_split<<<16, 256, 0, stream>>>(Wrm, wrmh, wrml, 4096);
  k_conv_hi<<<1024, 256, 0, stream>>>(Wproj, wph, 262144);
  k_conv_hi<<<16384, 256, 0, stream>>>(x, xh, 4194304);

  // all-batch fused pipeline (10 launches total)
  k_qkv_mfma<<<dim3(16, 128), 256, 0, stream>>>(xh, wh, wl, bqkv, ws);
  k_qkv_v<<<dim3(8, 128), 256, 0, stream>>>(xh, wh, bqkv, vb);
  k_pass_a_mfma<<<dim3(16, 16, 4), 256, 0, stream>>>(ws, vb, wrmh, wrml,
                                                     kvp, ws + DPART_OFF);
  k_reduce_t<<<dim3(8, 16, 4), 256, 0, stream>>>(kvp, ws + DPART_OFF,
                                                 kvt, ws + DENV_OFF);
  k_pass_b_mfma<<<dim3(32, 16, 4), 256, 0, stream>>>(ws, wrmh, wrml, kvt,
                                                     ws + DENV_OFF, ambf);
  k_out_mfma<<<dim3(8, 128), 256, 0, stream>>>(ambf, wph, bproj, out);
}